// Round 1
// baseline (1536.839 us; speedup 1.0000x reference)
//
#include <hip/hip_runtime.h>
#include <cstdint>

#define TPB 256

// ---------- degree / norm ----------
__global__ void k_deg(const int* __restrict__ col, int E, int* __restrict__ cnt){
  int e = blockIdx.x*blockDim.x + threadIdx.x;
  if (e < E) atomicAdd(&cnt[col[e]], 1);
}

__global__ void k_dis(const int* __restrict__ cnt, int N, float* __restrict__ dis){
  int n = blockIdx.x*blockDim.x + threadIdx.x;
  if (n < N){ int c = cnt[n]; dis[n] = (c > 0) ? rsqrtf((float)c) : 0.0f; }
}

// ---------- exclusive scan of cnt -> off (3 kernels) ----------
__global__ void k_scan1(const int* __restrict__ cnt, int N, int* __restrict__ out, int* __restrict__ bsums){
  __shared__ int wsum[4];
  int t = threadIdx.x;
  int base = blockIdx.x*1024 + t*4;
  int v0 = (base+0 < N) ? cnt[base+0] : 0;
  int v1 = (base+1 < N) ? cnt[base+1] : 0;
  int v2 = (base+2 < N) ? cnt[base+2] : 0;
  int v3 = (base+3 < N) ? cnt[base+3] : 0;
  int tot = v0+v1+v2+v3;
  int lane = t & 63, wid = t >> 6;
  int x = tot;
  for (int d = 1; d < 64; d <<= 1){ int y = __shfl_up(x, d); if (lane >= d) x += y; }
  if (lane == 63) wsum[wid] = x;
  __syncthreads();
  if (t == 0){ int a = 0; for (int w = 0; w < 4; w++){ int s = wsum[w]; wsum[w] = a; a += s; } bsums[blockIdx.x] = a; }
  __syncthreads();
  int run = x - tot + wsum[wid];
  if (base+0 < N) out[base+0] = run; run += v0;
  if (base+1 < N) out[base+1] = run; run += v1;
  if (base+2 < N) out[base+2] = run; run += v2;
  if (base+3 < N) out[base+3] = run;
}

__global__ void k_scan2(int* __restrict__ bsums, int nb){
  if (blockIdx.x == 0 && threadIdx.x == 0){
    int a = 0;
    for (int i = 0; i < nb; i++){ int s = bsums[i]; bsums[i] = a; a += s; }
  }
}

__global__ void k_scan3(int* __restrict__ off, int* __restrict__ cursor, const int* __restrict__ bsums, int N){
  int i = blockIdx.x*blockDim.x + threadIdx.x;
  if (i < N){
    int v = off[i] + bsums[i >> 10];
    off[i] = v;
    cursor[i] = v;
  }
}

// ---------- CSR bucket fill ----------
__global__ void k_fill(const int* __restrict__ row, const int* __restrict__ col, int E,
                       const float* __restrict__ dis, int* __restrict__ cursor,
                       int* __restrict__ eidx, float* __restrict__ enorm){
  int e = blockIdx.x*blockDim.x + threadIdx.x;
  if (e < E){
    int r = row[e], c = col[e];
    int p = atomicAdd(&cursor[c], 1);
    eidx[p]  = r;
    enorm[p] = dis[r]*dis[c];
  }
}

// ---------- fused FC1(4->32)+FC2(32->128), relu ----------
__global__ void k_fc12(const float* __restrict__ x,
                       const float* __restrict__ W1, const float* __restrict__ b1,
                       const float* __restrict__ W2, const float* __restrict__ b2,
                       float* __restrict__ h1, int N){
  __shared__ float sW1[4*32], sb1[32], sW2[32*128], sb2[128];
  int t = threadIdx.x;
  for (int i = t; i < 128;  i += TPB) sW1[i] = W1[i];
  for (int i = t; i < 32;   i += TPB) sb1[i] = b1[i];
  for (int i = t; i < 4096; i += TPB) sW2[i] = W2[i];
  for (int i = t; i < 128;  i += TPB) sb2[i] = b2[i];
  __syncthreads();
  int g = t >> 5, l = t & 31;
  int n = blockIdx.x*8 + g;
  if (n >= N) return;
  float xv0 = x[n*4+0], xv1 = x[n*4+1], xv2 = x[n*4+2], xv3 = x[n*4+3];
  float h = sb1[l] + xv0*sW1[0*32+l] + xv1*sW1[1*32+l] + xv2*sW1[2*32+l] + xv3*sW1[3*32+l];
  h = fmaxf(h, 0.f);
  float a0 = sb2[l], a1 = sb2[32+l], a2 = sb2[64+l], a3 = sb2[96+l];
  for (int j = 0; j < 32; j++){
    float hj = __shfl(h, j, 32);
    a0 += hj*sW2[j*128 + l];
    a1 += hj*sW2[j*128 + 32 + l];
    a2 += hj*sW2[j*128 + 64 + l];
    a3 += hj*sW2[j*128 + 96 + l];
  }
  h1[n*128 + l]      = fmaxf(a0, 0.f);
  h1[n*128 + 32 + l] = fmaxf(a1, 0.f);
  h1[n*128 + 64 + l] = fmaxf(a2, 0.f);
  h1[n*128 + 96 + l] = fmaxf(a3, 0.f);
}

// ---------- einsum: out[n, k*32+o] = sum_f h[n,f] * W[k,f,o] (+ bias[k,o]) ----------
// W layout [K=4][FIN][32]. f-tiled LDS staging (16 KB), 8 nodes/block, 32 threads/node.
template<int FIN, bool ADDB>
__global__ void k_mm(const float* __restrict__ h, const float* __restrict__ W,
                     const float* __restrict__ bias, float* __restrict__ out, int N){
  __shared__ float sW[4*32*32]; // [k][ftile][o]
  int t = threadIdx.x, g = t >> 5, l = t & 31;
  int n = blockIdx.x*8 + g;
  float acc0, acc1, acc2, acc3;
  if (ADDB && n < N){ acc0 = bias[l]; acc1 = bias[32+l]; acc2 = bias[64+l]; acc3 = bias[96+l]; }
  else { acc0 = acc1 = acc2 = acc3 = 0.f; }
  for (int f0 = 0; f0 < FIN; f0 += 32){
    __syncthreads();
    for (int i = t; i < 4096; i += TPB){
      int k = i >> 10, r = i & 1023, ft = r >> 5, o = r & 31;
      sW[i] = W[(k*FIN + f0 + ft)*32 + o];
    }
    __syncthreads();
    if (n < N){
      float hv = h[(size_t)n*FIN + f0 + l];
      for (int j = 0; j < 32; j++){
        float hj = __shfl(hv, j, 32);
        int b = (j << 5) + l;
        acc0 += hj*sW[b];
        acc1 += hj*sW[1024 + b];
        acc2 += hj*sW[2048 + b];
        acc3 += hj*sW[3072 + b];
      }
    }
  }
  if (n < N){
    size_t o = (size_t)n*128;
    out[o + l]      = acc0;
    out[o + 32 + l] = acc1;
    out[o + 64 + l] = acc2;
    out[o + 96 + l] = acc3;
  }
}

// ---------- CSR aggregation: agg[n,:] += sum_{e in(n)} norm_e * hk[src_e,:] ----------
__global__ void k_agg(const float* __restrict__ hk, const int* __restrict__ off, const int* __restrict__ cnt,
                      const int* __restrict__ eidx, const float* __restrict__ enorm,
                      float* __restrict__ agg, int N){
  int t = threadIdx.x, g = t >> 5, l = t & 31;
  int n = blockIdx.x*8 + g;
  if (n >= N) return;
  int s = off[n], c = cnt[n];
  float4 acc = make_float4(0.f, 0.f, 0.f, 0.f);
  for (int i = 0; i < c; i++){
    int   src = eidx[s+i];
    float w   = enorm[s+i];
    float4 v = *(const float4*)&hk[(size_t)src*128 + l*4];
    acc.x += w*v.x; acc.y += w*v.y; acc.z += w*v.z; acc.w += w*v.w;
  }
  float4* p = (float4*)&agg[(size_t)n*128 + l*4];
  float4 cur = *p;
  cur.x += acc.x; cur.y += acc.y; cur.z += acc.z; cur.w += acc.w;
  *p = cur;
}

// ---------- relu + mean over K ----------
__global__ void k_reduce(const float* __restrict__ agg, float* __restrict__ hout, int N){
  int i = blockIdx.x*blockDim.x + threadIdx.x;
  if (i < N*32){
    int n = i >> 5, o = i & 31;
    const float* p = &agg[(size_t)n*128 + o];
    float s = fmaxf(p[0],0.f) + fmaxf(p[32],0.f) + fmaxf(p[64],0.f) + fmaxf(p[96],0.f);
    hout[i] = 0.25f*s;
  }
}

// ---------- head: relu(h@W3+b3)@W4+b4 ----------
__global__ void k_head(const float* __restrict__ h,
                       const float* __restrict__ W3, const float* __restrict__ b3,
                       const float* __restrict__ W4, const float* __restrict__ b4,
                       float* __restrict__ out, int N){
  __shared__ float sW3[32*16], sb3[16], sW4[16*2], sb4[2];
  int t = threadIdx.x;
  for (int i = t; i < 512; i += TPB) sW3[i] = W3[i];
  if (t < 16) sb3[t] = b3[t];
  if (t < 32) sW4[t] = W4[t];
  if (t < 2)  sb4[t] = b4[t];
  __syncthreads();
  int n = blockIdx.x*TPB + t;
  if (n >= N) return;
  float hin[32];
  #pragma unroll
  for (int j = 0; j < 32; j++) hin[j] = h[(size_t)n*32 + j];
  float m[16];
  #pragma unroll
  for (int o = 0; o < 16; o++){
    float a = sb3[o];
    #pragma unroll
    for (int j = 0; j < 32; j++) a += hin[j]*sW3[j*16 + o];
    m[o] = fmaxf(a, 0.f);
  }
  float o0 = sb4[0], o1 = sb4[1];
  #pragma unroll
  for (int j = 0; j < 16; j++){ o0 += m[j]*sW4[j*2]; o1 += m[j]*sW4[j*2+1]; }
  out[(size_t)n*2]     = o0;
  out[(size_t)n*2 + 1] = o1;
}

extern "C" void kernel_launch(void* const* d_in, const int* in_sizes, int n_in,
                              void* d_out, int out_size, void* d_ws, size_t ws_size,
                              hipStream_t stream){
  const float* x     = (const float*)d_in[0];
  const int*   ei    = (const int*)  d_in[1];
  const float* fc1_w = (const float*)d_in[2];
  const float* fc1_b = (const float*)d_in[3];
  const float* fc2_w = (const float*)d_in[4];
  const float* fc2_b = (const float*)d_in[5];
  const float* a_iw[4] = {(const float*)d_in[6],  (const float*)d_in[9],  (const float*)d_in[12], (const float*)d_in[15]};
  const float* a_rw[4] = {(const float*)d_in[7],  (const float*)d_in[10], (const float*)d_in[13], (const float*)d_in[16]};
  const float* a_b [4] = {(const float*)d_in[8],  (const float*)d_in[11], (const float*)d_in[14], (const float*)d_in[17]};
  const float* fc3_w = (const float*)d_in[18];
  const float* fc3_b = (const float*)d_in[19];
  const float* fc4_w = (const float*)d_in[20];
  const float* fc4_b = (const float*)d_in[21];

  const int N = in_sizes[0] / 4;
  const int E = in_sizes[1] / 2;
  const int* row = ei;
  const int* col = ei + E;

  char* p = (char*)d_ws;
  auto alloc = [&](size_t bytes)->void*{
    void* q = (void*)p;
    p += (bytes + 255) & ~size_t(255);
    return q;
  };
  float* dis    = (float*)alloc((size_t)N*4);
  int*   cnt    = (int*)  alloc((size_t)N*4);
  int*   off    = (int*)  alloc((size_t)N*4);
  int*   cursor = (int*)  alloc((size_t)N*4);
  const int nb  = (N + 1023) / 1024;
  int*   bsums  = (int*)  alloc((size_t)nb*4);
  int*   eidx   = (int*)  alloc((size_t)E*4);
  float* enorm  = (float*)alloc((size_t)E*4);
  float* h1     = (float*)alloc((size_t)N*128*4);
  float* bufA   = (float*)alloc((size_t)N*128*4);
  float* bufB   = (float*)alloc((size_t)N*128*4);
  float* h2 = h1;                 // reuse: h1 dead after ARMA1's two mm's
  float* h3 = h1 + (size_t)N*32;

  hipMemsetAsync(cnt, 0, (size_t)N*4, stream);
  k_deg  <<<(E+TPB-1)/TPB, TPB, 0, stream>>>(col, E, cnt);
  k_dis  <<<(N+TPB-1)/TPB, TPB, 0, stream>>>(cnt, N, dis);
  k_scan1<<<nb, TPB, 0, stream>>>(cnt, N, off, bsums);
  k_scan2<<<1, 1, 0, stream>>>(bsums, nb);
  k_scan3<<<(N+TPB-1)/TPB, TPB, 0, stream>>>(off, cursor, bsums, N);
  k_fill <<<(E+TPB-1)/TPB, TPB, 0, stream>>>(row, col, E, dis, cursor, eidx, enorm);

  k_fc12 <<<(N+7)/8, TPB, 0, stream>>>(x, fc1_w, fc1_b, fc2_w, fc2_b, h1, N);

  // ARMA 1 (fin=128): h1 -> h2
  k_mm<128,false><<<(N+7)/8, TPB, 0, stream>>>(h1, a_iw[0], nullptr, bufA, N);
  k_mm<128,true ><<<(N+7)/8, TPB, 0, stream>>>(h1, a_rw[0], a_b[0],  bufB, N);
  k_agg   <<<(N+7)/8, TPB, 0, stream>>>(bufA, off, cnt, eidx, enorm, bufB, N);
  k_reduce<<<((size_t)N*32+TPB-1)/TPB, TPB, 0, stream>>>(bufB, h2, N);

  // ARMA 2..4 (fin=32): ping-pong h2 <-> h3
  const float* hin = h2; float* hout = h3;
  for (int L = 1; L < 4; L++){
    k_mm<32,false><<<(N+7)/8, TPB, 0, stream>>>(hin, a_iw[L], nullptr, bufA, N);
    k_mm<32,true ><<<(N+7)/8, TPB, 0, stream>>>(hin, a_rw[L], a_b[L],  bufB, N);
    k_agg   <<<(N+7)/8, TPB, 0, stream>>>(bufA, off, cnt, eidx, enorm, bufB, N);
    k_reduce<<<((size_t)N*32+TPB-1)/TPB, TPB, 0, stream>>>(bufB, hout, N);
    const float* tmp = hin; hin = hout; hout = (float*)tmp;
  }

  // hin now points at ARMA4 output (h3 after 3 swaps... verify: L1: in h2 out h3 -> swap(in=h3,out=h2);
  // L2: in h3 out h2 -> swap(in=h2,out=h3); L3: in h2 out h3 -> swap(in=h3,out=h2). Final output buffer = h3.
  k_head<<<(N+TPB-1)/TPB, TPB, 0, stream>>>(h3, fc3_w, fc3_b, fc4_w, fc4_b, (float*)d_out, N);
}

// Round 2
// 1045.051 us; speedup vs baseline: 1.4706x; 1.4706x over previous
//
#include <hip/hip_runtime.h>
#include <cstdint>

#define TPB 256

// ---------- degree / norm ----------
__global__ void k_deg(const int* __restrict__ col, int E, int* __restrict__ cnt){
  int e = blockIdx.x*blockDim.x + threadIdx.x;
  if (e < E) atomicAdd(&cnt[col[e]], 1);
}

__global__ void k_dis(const int* __restrict__ cnt, int N, float* __restrict__ dis){
  int n = blockIdx.x*blockDim.x + threadIdx.x;
  if (n < N){ int c = cnt[n]; dis[n] = (c > 0) ? rsqrtf((float)c) : 0.0f; }
}

// ---------- exclusive scan of cnt -> off ----------
__global__ void k_scan1(const int* __restrict__ cnt, int N, int* __restrict__ out, int* __restrict__ bsums){
  __shared__ int wsum[4];
  int t = threadIdx.x;
  int base = blockIdx.x*1024 + t*4;
  int v0 = (base+0 < N) ? cnt[base+0] : 0;
  int v1 = (base+1 < N) ? cnt[base+1] : 0;
  int v2 = (base+2 < N) ? cnt[base+2] : 0;
  int v3 = (base+3 < N) ? cnt[base+3] : 0;
  int tot = v0+v1+v2+v3;
  int lane = t & 63, wid = t >> 6;
  int x = tot;
  for (int d = 1; d < 64; d <<= 1){ int y = __shfl_up(x, d); if (lane >= d) x += y; }
  if (lane == 63) wsum[wid] = x;
  __syncthreads();
  if (t == 0){ int a = 0; for (int w = 0; w < 4; w++){ int s = wsum[w]; wsum[w] = a; a += s; } bsums[blockIdx.x] = a; }
  __syncthreads();
  int run = x - tot + wsum[wid];
  if (base+0 < N) out[base+0] = run; run += v0;
  if (base+1 < N) out[base+1] = run; run += v1;
  if (base+2 < N) out[base+2] = run; run += v2;
  if (base+3 < N) out[base+3] = run;
}

__global__ void k_scan2(int* __restrict__ bsums, int nb){
  if (blockIdx.x == 0 && threadIdx.x == 0){
    int a = 0;
    for (int i = 0; i < nb; i++){ int s = bsums[i]; bsums[i] = a; a += s; }
  }
}

__global__ void k_scan3(int* __restrict__ off, int* __restrict__ cursor, const int* __restrict__ bsums, int N){
  int i = blockIdx.x*blockDim.x + threadIdx.x;
  if (i < N){
    int v = off[i] + bsums[i >> 10];
    off[i] = v;
    cursor[i] = v;
  }
}

// ---------- CSR bucket fill ----------
__global__ void k_fill(const int* __restrict__ row, const int* __restrict__ col, int E,
                       const float* __restrict__ dis, int* __restrict__ cursor,
                       int* __restrict__ eidx, float* __restrict__ enorm){
  int e = blockIdx.x*blockDim.x + threadIdx.x;
  if (e < E){
    int r = row[e], c = col[e];
    int p = atomicAdd(&cursor[c], 1);
    eidx[p]  = r;
    enorm[p] = dis[r]*dis[c];
  }
}

// ---------- fc1: x(N,4) -> relu(x@W1+b1) (N,32) ----------
__global__ void k_fc1(const float* __restrict__ x, const float* __restrict__ W1,
                      const float* __restrict__ b1, float* __restrict__ hmid, int N){
  __shared__ float sW[128], sb[32];
  int t = threadIdx.x;
  if (t < 128) sW[t] = W1[t];
  if (t < 32)  sb[t] = b1[t];
  __syncthreads();
  int i = blockIdx.x*TPB + t;
  if (i >= N*32) return;
  int n = i >> 5, o = i & 31;
  float4 xv = *(const float4*)&x[(size_t)n*4];
  float a = sb[o] + xv.x*sW[o] + xv.y*sW[32+o] + xv.z*sW[64+o] + xv.w*sW[96+o];
  hmid[i] = fmaxf(a, 0.f);
}

// ---------- register-tiled GEMM: out(N,128) = h(N,FIN) @ W2d(FIN,128) [+bias][relu] ----------
// KSTACK: W stored [K=4][FIN][32] -> W2d[f][k*32+o]; else W stored flat [FIN][128].
// 64 nodes x 128 outs per block; thread tile 4 nodes x 8 outs.
template<int FIN, bool KSTACK, bool ADDB, bool RELU>
__global__ void k_mm1(const float* __restrict__ h, const float* __restrict__ W,
                      const float* __restrict__ bias, float* __restrict__ out, int N){
  __shared__ float sW[32*128];
  __shared__ float sHT[32*68];
  int t = threadIdx.x;
  int n0 = blockIdx.x*64;
  int tn = t & 15, to = t >> 4;
  float acc[4][8];
  if (ADDB){
    float4 b0 = *(const float4*)&bias[8*to];
    float4 b1 = *(const float4*)&bias[8*to+4];
    float bb[8] = {b0.x,b0.y,b0.z,b0.w,b1.x,b1.y,b1.z,b1.w};
    #pragma unroll
    for (int i = 0; i < 4; i++)
      #pragma unroll
      for (int j = 0; j < 8; j++) acc[i][j] = bb[j];
  } else {
    #pragma unroll
    for (int i = 0; i < 4; i++)
      #pragma unroll
      for (int j = 0; j < 8; j++) acc[i][j] = 0.f;
  }

  for (int f0 = 0; f0 < FIN; f0 += 32){
    __syncthreads();
    #pragma unroll
    for (int j = 0; j < 4; j++){
      int flat = (t + j*256)*4;
      int f = flat >> 7, ko = flat & 127;
      int src;
      if (KSTACK){ int k = ko >> 5, o = ko & 31; src = (k*FIN + f0 + f)*32 + o; }
      else       { src = (f0 + f)*128 + ko; }
      *(float4*)&sW[flat] = *(const float4*)&W[src];
    }
    #pragma unroll
    for (int j = 0; j < 2; j++){
      int flat = (t + j*256)*4;
      int nl = flat >> 5, f = flat & 31;
      int n = n0 + nl;
      float4 hv = make_float4(0.f,0.f,0.f,0.f);
      if (n < N) hv = *(const float4*)&h[(size_t)n*FIN + f0 + f];
      sHT[(f+0)*68 + nl] = hv.x;
      sHT[(f+1)*68 + nl] = hv.y;
      sHT[(f+2)*68 + nl] = hv.z;
      sHT[(f+3)*68 + nl] = hv.w;
    }
    __syncthreads();
    #pragma unroll 4
    for (int f = 0; f < 32; f++){
      float4 hv = *(float4*)&sHT[f*68 + 4*tn];
      float4 a0 = *(float4*)&sW[f*128 + 8*to];
      float4 a1 = *(float4*)&sW[f*128 + 8*to + 4];
      float hh[4] = {hv.x,hv.y,hv.z,hv.w};
      float wa[8] = {a0.x,a0.y,a0.z,a0.w,a1.x,a1.y,a1.z,a1.w};
      #pragma unroll
      for (int i = 0; i < 4; i++)
        #pragma unroll
        for (int j = 0; j < 8; j++) acc[i][j] += hh[i]*wa[j];
    }
  }

  #pragma unroll
  for (int i = 0; i < 4; i++){
    int n = n0 + 4*tn + i;
    if (n < N){
      float4 v0, v1;
      v0.x = acc[i][0]; v0.y = acc[i][1]; v0.z = acc[i][2]; v0.w = acc[i][3];
      v1.x = acc[i][4]; v1.y = acc[i][5]; v1.z = acc[i][6]; v1.w = acc[i][7];
      if (RELU){
        v0.x = fmaxf(v0.x,0.f); v0.y = fmaxf(v0.y,0.f); v0.z = fmaxf(v0.z,0.f); v0.w = fmaxf(v0.w,0.f);
        v1.x = fmaxf(v1.x,0.f); v1.y = fmaxf(v1.y,0.f); v1.z = fmaxf(v1.z,0.f); v1.w = fmaxf(v1.w,0.f);
      }
      *(float4*)&out[(size_t)n*128 + 8*to]     = v0;
      *(float4*)&out[(size_t)n*128 + 8*to + 4] = v1;
    }
  }
}

// ---------- dual GEMM for ARMA: outA = h@iw, outB = h@rw + b (shared h read) ----------
template<int FIN>
__global__ void k_mm2(const float* __restrict__ h,
                      const float* __restrict__ Wa, const float* __restrict__ Wb,
                      const float* __restrict__ bias,
                      float* __restrict__ outA, float* __restrict__ outB, int N){
  __shared__ float sWa[32*128];
  __shared__ float sWb[32*128];
  __shared__ float sHT[32*68];
  int t = threadIdx.x;
  int n0 = blockIdx.x*64;
  int tn = t & 15, to = t >> 4;
  float accA[4][8], accB[4][8];
  {
    float4 b0 = *(const float4*)&bias[8*to];
    float4 b1 = *(const float4*)&bias[8*to+4];
    float bb[8] = {b0.x,b0.y,b0.z,b0.w,b1.x,b1.y,b1.z,b1.w};
    #pragma unroll
    for (int i = 0; i < 4; i++)
      #pragma unroll
      for (int j = 0; j < 8; j++){ accA[i][j] = 0.f; accB[i][j] = bb[j]; }
  }

  for (int f0 = 0; f0 < FIN; f0 += 32){
    __syncthreads();
    #pragma unroll
    for (int j = 0; j < 4; j++){
      int flat = (t + j*256)*4;
      int f = flat >> 7, ko = flat & 127;
      int k = ko >> 5, o = ko & 31;
      int src = (k*FIN + f0 + f)*32 + o;
      *(float4*)&sWa[flat] = *(const float4*)&Wa[src];
      *(float4*)&sWb[flat] = *(const float4*)&Wb[src];
    }
    #pragma unroll
    for (int j = 0; j < 2; j++){
      int flat = (t + j*256)*4;
      int nl = flat >> 5, f = flat & 31;
      int n = n0 + nl;
      float4 hv = make_float4(0.f,0.f,0.f,0.f);
      if (n < N) hv = *(const float4*)&h[(size_t)n*FIN + f0 + f];
      sHT[(f+0)*68 + nl] = hv.x;
      sHT[(f+1)*68 + nl] = hv.y;
      sHT[(f+2)*68 + nl] = hv.z;
      sHT[(f+3)*68 + nl] = hv.w;
    }
    __syncthreads();
    #pragma unroll 4
    for (int f = 0; f < 32; f++){
      float4 hv = *(float4*)&sHT[f*68 + 4*tn];
      float4 a0 = *(float4*)&sWa[f*128 + 8*to];
      float4 a1 = *(float4*)&sWa[f*128 + 8*to + 4];
      float4 b0 = *(float4*)&sWb[f*128 + 8*to];
      float4 b1 = *(float4*)&sWb[f*128 + 8*to + 4];
      float hh[4] = {hv.x,hv.y,hv.z,hv.w};
      float wa[8] = {a0.x,a0.y,a0.z,a0.w,a1.x,a1.y,a1.z,a1.w};
      float wb[8] = {b0.x,b0.y,b0.z,b0.w,b1.x,b1.y,b1.z,b1.w};
      #pragma unroll
      for (int i = 0; i < 4; i++)
        #pragma unroll
        for (int j = 0; j < 8; j++){
          accA[i][j] += hh[i]*wa[j];
          accB[i][j] += hh[i]*wb[j];
        }
    }
  }

  #pragma unroll
  for (int i = 0; i < 4; i++){
    int n = n0 + 4*tn + i;
    if (n < N){
      float4 vA0, vA1, vB0, vB1;
      vA0.x=accA[i][0]; vA0.y=accA[i][1]; vA0.z=accA[i][2]; vA0.w=accA[i][3];
      vA1.x=accA[i][4]; vA1.y=accA[i][5]; vA1.z=accA[i][6]; vA1.w=accA[i][7];
      vB0.x=accB[i][0]; vB0.y=accB[i][1]; vB0.z=accB[i][2]; vB0.w=accB[i][3];
      vB1.x=accB[i][4]; vB1.y=accB[i][5]; vB1.z=accB[i][6]; vB1.w=accB[i][7];
      *(float4*)&outA[(size_t)n*128 + 8*to]     = vA0;
      *(float4*)&outA[(size_t)n*128 + 8*to + 4] = vA1;
      *(float4*)&outB[(size_t)n*128 + 8*to]     = vB0;
      *(float4*)&outB[(size_t)n*128 + 8*to + 4] = vB1;
    }
  }
}

// ---------- CSR aggregation fused with root+relu+mean-over-K ----------
// hout[n,o] = 0.25 * sum_k relu( sum_e norm*hk[src,k*32+o] + root[n,k*32+o] )
__global__ void k_agg(const float* __restrict__ hk, const float* __restrict__ root,
                      const int* __restrict__ off, const int* __restrict__ cnt,
                      const int* __restrict__ eidx, const float* __restrict__ enorm,
                      float* __restrict__ hout, int N){
  int t = threadIdx.x, g = t >> 5, l = t & 31;
  int n = blockIdx.x*8 + g;
  if (n >= N) return;
  int s = off[n], c = cnt[n];
  float4 acc = make_float4(0.f,0.f,0.f,0.f);
  for (int i = 0; i < c; i++){
    int   src = eidx[s+i];
    float w   = enorm[s+i];
    float4 v = *(const float4*)&hk[(size_t)src*128 + l*4];
    acc.x += w*v.x; acc.y += w*v.y; acc.z += w*v.z; acc.w += w*v.w;
  }
  float4 r = *(const float4*)&root[(size_t)n*128 + l*4];
  acc.x = fmaxf(acc.x + r.x, 0.f);
  acc.y = fmaxf(acc.y + r.y, 0.f);
  acc.z = fmaxf(acc.z + r.z, 0.f);
  acc.w = fmaxf(acc.w + r.w, 0.f);
  // sum over the 4 k-stacks: lanes l, l^8, l^16 hold same o-quad (ko = 4l)
  acc.x += __shfl_xor(acc.x, 8);  acc.y += __shfl_xor(acc.y, 8);
  acc.z += __shfl_xor(acc.z, 8);  acc.w += __shfl_xor(acc.w, 8);
  acc.x += __shfl_xor(acc.x, 16); acc.y += __shfl_xor(acc.y, 16);
  acc.z += __shfl_xor(acc.z, 16); acc.w += __shfl_xor(acc.w, 16);
  if (l < 8){
    float4 o4;
    o4.x = 0.25f*acc.x; o4.y = 0.25f*acc.y; o4.z = 0.25f*acc.z; o4.w = 0.25f*acc.w;
    *(float4*)&hout[(size_t)n*32 + 4*l] = o4;
  }
}

// ---------- head: relu(h@W3+b3)@W4+b4 ----------
__global__ void k_head(const float* __restrict__ h,
                       const float* __restrict__ W3, const float* __restrict__ b3,
                       const float* __restrict__ W4, const float* __restrict__ b4,
                       float* __restrict__ out, int N){
  __shared__ float sW3[32*16], sb3[16], sW4[16*2], sb4[2];
  int t = threadIdx.x;
  for (int i = t; i < 512; i += TPB) sW3[i] = W3[i];
  if (t < 16) sb3[t] = b3[t];
  if (t < 32) sW4[t] = W4[t];
  if (t < 2)  sb4[t] = b4[t];
  __syncthreads();
  int n = blockIdx.x*TPB + t;
  if (n >= N) return;
  float hin[32];
  #pragma unroll
  for (int j = 0; j < 32; j++) hin[j] = h[(size_t)n*32 + j];
  float m[16];
  #pragma unroll
  for (int o = 0; o < 16; o++){
    float a = sb3[o];
    #pragma unroll
    for (int j = 0; j < 32; j++) a += hin[j]*sW3[j*16 + o];
    m[o] = fmaxf(a, 0.f);
  }
  float o0 = sb4[0], o1 = sb4[1];
  #pragma unroll
  for (int j = 0; j < 16; j++){ o0 += m[j]*sW4[j*2]; o1 += m[j]*sW4[j*2+1]; }
  out[(size_t)n*2]     = o0;
  out[(size_t)n*2 + 1] = o1;
}

extern "C" void kernel_launch(void* const* d_in, const int* in_sizes, int n_in,
                              void* d_out, int out_size, void* d_ws, size_t ws_size,
                              hipStream_t stream){
  const float* x     = (const float*)d_in[0];
  const int*   ei    = (const int*)  d_in[1];
  const float* fc1_w = (const float*)d_in[2];
  const float* fc1_b = (const float*)d_in[3];
  const float* fc2_w = (const float*)d_in[4];
  const float* fc2_b = (const float*)d_in[5];
  const float* a_iw[4] = {(const float*)d_in[6],  (const float*)d_in[9],  (const float*)d_in[12], (const float*)d_in[15]};
  const float* a_rw[4] = {(const float*)d_in[7],  (const float*)d_in[10], (const float*)d_in[13], (const float*)d_in[16]};
  const float* a_b [4] = {(const float*)d_in[8],  (const float*)d_in[11], (const float*)d_in[14], (const float*)d_in[17]};
  const float* fc3_w = (const float*)d_in[18];
  const float* fc3_b = (const float*)d_in[19];
  const float* fc4_w = (const float*)d_in[20];
  const float* fc4_b = (const float*)d_in[21];

  const int N = in_sizes[0] / 4;
  const int E = in_sizes[1] / 2;
  const int* row = ei;
  const int* col = ei + E;

  char* p = (char*)d_ws;
  auto alloc = [&](size_t bytes)->void*{
    void* q = (void*)p;
    p += (bytes + 255) & ~size_t(255);
    return q;
  };
  float* dis    = (float*)alloc((size_t)N*4);
  int*   cnt    = (int*)  alloc((size_t)N*4);
  int*   off    = (int*)  alloc((size_t)N*4);
  int*   cursor = (int*)  alloc((size_t)N*4);
  const int nb  = (N + 1023) / 1024;
  int*   bsums  = (int*)  alloc((size_t)nb*4);
  int*   eidx   = (int*)  alloc((size_t)E*4);
  float* enorm  = (float*)alloc((size_t)E*4);
  float* h1     = (float*)alloc((size_t)N*128*4);
  float* bufA   = (float*)alloc((size_t)N*128*4);
  float* bufB   = (float*)alloc((size_t)N*128*4);
  float* hmid = bufB;             // N*32, dead after fc2
  float* h2 = h1;                 // N*32, reuse h1 region (dead after ARMA1 mm)
  float* h3 = h1 + (size_t)N*32;

  hipMemsetAsync(cnt, 0, (size_t)N*4, stream);
  k_deg  <<<(E+TPB-1)/TPB, TPB, 0, stream>>>(col, E, cnt);
  k_dis  <<<(N+TPB-1)/TPB, TPB, 0, stream>>>(cnt, N, dis);
  k_scan1<<<nb, TPB, 0, stream>>>(cnt, N, off, bsums);
  k_scan2<<<1, 1, 0, stream>>>(bsums, nb);
  k_scan3<<<(N+TPB-1)/TPB, TPB, 0, stream>>>(off, cursor, bsums, N);
  k_fill <<<(E+TPB-1)/TPB, TPB, 0, stream>>>(row, col, E, dis, cursor, eidx, enorm);

  const int gmm = (N + 63) / 64;
  k_fc1<<<((size_t)N*32+TPB-1)/TPB, TPB, 0, stream>>>(x, fc1_w, fc1_b, hmid, N);
  k_mm1<32,false,true,true><<<gmm, TPB, 0, stream>>>(hmid, fc2_w, fc2_b, h1, N);

  // ARMA 1 (fin=128): h1 -> h2
  k_mm2<128><<<gmm, TPB, 0, stream>>>(h1, a_iw[0], a_rw[0], a_b[0], bufA, bufB, N);
  k_agg<<<(N+7)/8, TPB, 0, stream>>>(bufA, bufB, off, cnt, eidx, enorm, h2, N);

  // ARMA 2..4 (fin=32): ping-pong h2 <-> h3
  const float* hin = h2; float* hout = h3;
  for (int L = 1; L < 4; L++){
    k_mm2<32><<<gmm, TPB, 0, stream>>>(hin, a_iw[L], a_rw[L], a_b[L], bufA, bufB, N);
    k_agg<<<(N+7)/8, TPB, 0, stream>>>(bufA, bufB, off, cnt, eidx, enorm, hout, N);
    const float* tmp = hin; hin = hout; hout = (float*)tmp;
  }

  // final ARMA output lives in h3 (L1: h2->h3, L2: h3->h2, L3: h2->h3)
  k_head<<<(N+TPB-1)/TPB, TPB, 0, stream>>>(h3, fc3_w, fc3_b, fc4_w, fc4_b, (float*)d_out, N);
}

// Round 3
// 784.911 us; speedup vs baseline: 1.9580x; 1.3314x over previous
//
#include <hip/hip_runtime.h>
#include <cstdint>

#define TPB 256

// ---------- degree / norm ----------
__global__ void k_deg(const int* __restrict__ col, int E, int* __restrict__ cnt){
  int e = blockIdx.x*blockDim.x + threadIdx.x;
  if (e < E) atomicAdd(&cnt[col[e]], 1);
}

__global__ void k_dis(const int* __restrict__ cnt, int N, float* __restrict__ dis){
  int n = blockIdx.x*blockDim.x + threadIdx.x;
  if (n < N){ int c = cnt[n]; dis[n] = (c > 0) ? rsqrtf((float)c) : 0.0f; }
}

// ---------- exclusive scan of cnt -> off ----------
__global__ void k_scan1(const int* __restrict__ cnt, int N, int* __restrict__ out, int* __restrict__ bsums){
  __shared__ int wsum[4];
  int t = threadIdx.x;
  int base = blockIdx.x*1024 + t*4;
  int v0 = (base+0 < N) ? cnt[base+0] : 0;
  int v1 = (base+1 < N) ? cnt[base+1] : 0;
  int v2 = (base+2 < N) ? cnt[base+2] : 0;
  int v3 = (base+3 < N) ? cnt[base+3] : 0;
  int tot = v0+v1+v2+v3;
  int lane = t & 63, wid = t >> 6;
  int x = tot;
  for (int d = 1; d < 64; d <<= 1){ int y = __shfl_up(x, d); if (lane >= d) x += y; }
  if (lane == 63) wsum[wid] = x;
  __syncthreads();
  if (t == 0){ int a = 0; for (int w = 0; w < 4; w++){ int s = wsum[w]; wsum[w] = a; a += s; } bsums[blockIdx.x] = a; }
  __syncthreads();
  int run = x - tot + wsum[wid];
  if (base+0 < N) out[base+0] = run; run += v0;
  if (base+1 < N) out[base+1] = run; run += v1;
  if (base+2 < N) out[base+2] = run; run += v2;
  if (base+3 < N) out[base+3] = run;
}

__global__ void k_scan2(int* __restrict__ bsums, int nb){
  if (blockIdx.x == 0 && threadIdx.x == 0){
    int a = 0;
    for (int i = 0; i < nb; i++){ int s = bsums[i]; bsums[i] = a; a += s; }
  }
}

__global__ void k_scan3(int* __restrict__ off, int* __restrict__ cursor, const int* __restrict__ bsums, int N){
  int i = blockIdx.x*blockDim.x + threadIdx.x;
  if (i < N){
    int v = off[i] + bsums[i >> 10];
    off[i] = v;
    cursor[i] = v;
  }
}

// ---------- CSR bucket fill ----------
__global__ void k_fill(const int* __restrict__ row, const int* __restrict__ col, int E,
                       const float* __restrict__ dis, int* __restrict__ cursor,
                       int* __restrict__ eidx, float* __restrict__ enorm){
  int e = blockIdx.x*blockDim.x + threadIdx.x;
  if (e < E){
    int r = row[e], c = col[e];
    int p = atomicAdd(&cursor[c], 1);
    eidx[p]  = r;
    enorm[p] = dis[r]*dis[c];
  }
}

// ---------- fc1: x(N,4) -> relu(x@W1+b1) (N,32) ----------
__global__ void k_fc1(const float* __restrict__ x, const float* __restrict__ W1,
                      const float* __restrict__ b1, float* __restrict__ hmid, int N){
  __shared__ float sW[128], sb[32];
  int t = threadIdx.x;
  if (t < 128) sW[t] = W1[t];
  if (t < 32)  sb[t] = b1[t];
  __syncthreads();
  int i = blockIdx.x*TPB + t;
  if (i >= N*32) return;
  int n = i >> 5, o = i & 31;
  float4 xv = *(const float4*)&x[(size_t)n*4];
  float a = sb[o] + xv.x*sW[o] + xv.y*sW[32+o] + xv.z*sW[64+o] + xv.w*sW[96+o];
  hmid[i] = fmaxf(a, 0.f);
}

// ---------- fc2 GEMM: h1(N,128) = relu(hmid(N,32) @ W2(32,128) + b2) ----------
__global__ void k_fc2(const float* __restrict__ h, const float* __restrict__ W,
                      const float* __restrict__ bias, float* __restrict__ out, int N){
  __shared__ float sW[32*128];
  __shared__ float sHT[32*68];
  int t = threadIdx.x;
  int n0 = blockIdx.x*64;
  int tn = t & 15, to = t >> 4;
  float acc[4][8];
  {
    float4 b0 = *(const float4*)&bias[8*to];
    float4 b1 = *(const float4*)&bias[8*to+4];
    float bb[8] = {b0.x,b0.y,b0.z,b0.w,b1.x,b1.y,b1.z,b1.w};
    #pragma unroll
    for (int i = 0; i < 4; i++)
      #pragma unroll
      for (int j = 0; j < 8; j++) acc[i][j] = bb[j];
  }
  #pragma unroll
  for (int j = 0; j < 4; j++){
    int flat = (t + j*256)*4;
    *(float4*)&sW[flat] = *(const float4*)&W[flat];
  }
  #pragma unroll
  for (int j = 0; j < 2; j++){
    int flat = (t + j*256)*4;
    int nl = flat >> 5, f = flat & 31;
    int n = n0 + nl;
    float4 hv = make_float4(0.f,0.f,0.f,0.f);
    if (n < N) hv = *(const float4*)&h[(size_t)n*32 + f];
    sHT[(f+0)*68 + nl] = hv.x;
    sHT[(f+1)*68 + nl] = hv.y;
    sHT[(f+2)*68 + nl] = hv.z;
    sHT[(f+3)*68 + nl] = hv.w;
  }
  __syncthreads();
  #pragma unroll 4
  for (int f = 0; f < 32; f++){
    float4 hv = *(float4*)&sHT[f*68 + 4*tn];
    float4 a0 = *(float4*)&sW[f*128 + 8*to];
    float4 a1 = *(float4*)&sW[f*128 + 8*to + 4];
    float hh[4] = {hv.x,hv.y,hv.z,hv.w};
    float wa[8] = {a0.x,a0.y,a0.z,a0.w,a1.x,a1.y,a1.z,a1.w};
    #pragma unroll
    for (int i = 0; i < 4; i++)
      #pragma unroll
      for (int j = 0; j < 8; j++) acc[i][j] += hh[i]*wa[j];
  }
  #pragma unroll
  for (int i = 0; i < 4; i++){
    int n = n0 + 4*tn + i;
    if (n < N){
      float4 v0, v1;
      v0.x = fmaxf(acc[i][0],0.f); v0.y = fmaxf(acc[i][1],0.f);
      v0.z = fmaxf(acc[i][2],0.f); v0.w = fmaxf(acc[i][3],0.f);
      v1.x = fmaxf(acc[i][4],0.f); v1.y = fmaxf(acc[i][5],0.f);
      v1.z = fmaxf(acc[i][6],0.f); v1.w = fmaxf(acc[i][7],0.f);
      *(float4*)&out[(size_t)n*128 + 8*to]     = v0;
      *(float4*)&out[(size_t)n*128 + 8*to + 4] = v1;
    }
  }
}

// ---------- CSR gather of raw features: aggH[n,:] = sum_e norm * h[src,:]  (FIN floats) ----------
template<int FIN>
__global__ void k_gather(const float* __restrict__ h, const int* __restrict__ off,
                         const int* __restrict__ cnt, const int* __restrict__ eidx,
                         const float* __restrict__ enorm, float* __restrict__ aggH, int N){
  constexpr int LPN = FIN/4;              // lanes per node (float4 each)
  constexpr int NPB = TPB/LPN;            // nodes per block
  int t = threadIdx.x;
  int g = t / LPN, l = t % LPN;
  int n = blockIdx.x*NPB + g;
  if (n >= N) return;
  int s = off[n], c = cnt[n];
  float4 acc = make_float4(0.f,0.f,0.f,0.f);
  int i = 0;
  for (; i + 1 < c; i += 2){
    int   s0 = eidx[s+i],   s1 = eidx[s+i+1];
    float w0 = enorm[s+i],  w1 = enorm[s+i+1];
    float4 v0 = *(const float4*)&h[(size_t)s0*FIN + l*4];
    float4 v1 = *(const float4*)&h[(size_t)s1*FIN + l*4];
    acc.x += w0*v0.x + w1*v1.x;
    acc.y += w0*v0.y + w1*v1.y;
    acc.z += w0*v0.z + w1*v1.z;
    acc.w += w0*v0.w + w1*v1.w;
  }
  if (i < c){
    int   s0 = eidx[s+i];
    float w0 = enorm[s+i];
    float4 v0 = *(const float4*)&h[(size_t)s0*FIN + l*4];
    acc.x += w0*v0.x; acc.y += w0*v0.y; acc.z += w0*v0.z; acc.w += w0*v0.w;
  }
  *(float4*)&aggH[(size_t)n*FIN + l*4] = acc;
}

// ---------- fused ARMA transform: out[n,o] = 0.25*sum_k relu(aggH[n]@iw_k + h[n]@rw_k + b_k)[o] ----------
// 64 nodes/block. Thread: tn=t>>5 (8 groups of 8 nodes), to=t&31 (one output col, all 4 stacks).
template<int FIN>
__global__ void k_arma(const float* __restrict__ aggH, const float* __restrict__ h,
                       const float* __restrict__ iw, const float* __restrict__ rw,
                       const float* __restrict__ bias, float* __restrict__ out, int N){
  __shared__ float sIW[32*128];  // [f_tile][k*32+o]
  __shared__ float sRW[32*128];
  __shared__ float sA[32*68];    // [f][node]
  __shared__ float sH[32*68];
  int t = threadIdx.x;
  int tn = t >> 5, to = t & 31;
  int n0 = blockIdx.x*64;
  float acc[8][4];
  #pragma unroll
  for (int i = 0; i < 8; i++)
    #pragma unroll
    for (int k = 0; k < 4; k++) acc[i][k] = 0.f;

  for (int f0 = 0; f0 < FIN; f0 += 32){
    __syncthreads();
    #pragma unroll
    for (int j = 0; j < 4; j++){
      int flat = (t + j*256)*4;
      int f = flat >> 7, ko = flat & 127;
      int k = ko >> 5, o = ko & 31;
      int src = (k*FIN + f0 + f)*32 + o;
      *(float4*)&sIW[flat] = *(const float4*)&iw[src];
      *(float4*)&sRW[flat] = *(const float4*)&rw[src];
    }
    #pragma unroll
    for (int j = 0; j < 2; j++){
      int flat = (t + j*256)*4;
      int nl = flat >> 5, f = flat & 31;
      int n = n0 + nl;
      float4 av = make_float4(0.f,0.f,0.f,0.f);
      float4 hv = make_float4(0.f,0.f,0.f,0.f);
      if (n < N){
        av = *(const float4*)&aggH[(size_t)n*FIN + f0 + f];
        hv = *(const float4*)&h[(size_t)n*FIN + f0 + f];
      }
      sA[(f+0)*68 + nl] = av.x; sA[(f+1)*68 + nl] = av.y;
      sA[(f+2)*68 + nl] = av.z; sA[(f+3)*68 + nl] = av.w;
      sH[(f+0)*68 + nl] = hv.x; sH[(f+1)*68 + nl] = hv.y;
      sH[(f+2)*68 + nl] = hv.z; sH[(f+3)*68 + nl] = hv.w;
    }
    __syncthreads();
    #pragma unroll 2
    for (int f = 0; f < 32; f++){
      float4 a0 = *(float4*)&sA[f*68 + 8*tn];
      float4 a1 = *(float4*)&sA[f*68 + 8*tn + 4];
      float4 h0 = *(float4*)&sH[f*68 + 8*tn];
      float4 h1 = *(float4*)&sH[f*68 + 8*tn + 4];
      float wi[4], wr[4];
      #pragma unroll
      for (int k = 0; k < 4; k++){
        wi[k] = sIW[f*128 + k*32 + to];
        wr[k] = sRW[f*128 + k*32 + to];
      }
      float av[8] = {a0.x,a0.y,a0.z,a0.w,a1.x,a1.y,a1.z,a1.w};
      float hv[8] = {h0.x,h0.y,h0.z,h0.w,h1.x,h1.y,h1.z,h1.w};
      #pragma unroll
      for (int i = 0; i < 8; i++)
        #pragma unroll
        for (int k = 0; k < 4; k++)
          acc[i][k] += av[i]*wi[k] + hv[i]*wr[k];
    }
  }

  float bb[4];
  #pragma unroll
  for (int k = 0; k < 4; k++) bb[k] = bias[k*32 + to];
  #pragma unroll
  for (int i = 0; i < 8; i++){
    int n = n0 + 8*tn + i;
    if (n < N){
      float s = fmaxf(acc[i][0]+bb[0],0.f) + fmaxf(acc[i][1]+bb[1],0.f)
              + fmaxf(acc[i][2]+bb[2],0.f) + fmaxf(acc[i][3]+bb[3],0.f);
      out[(size_t)n*32 + to] = 0.25f*s;
    }
  }
}

// ---------- head: relu(h@W3+b3)@W4+b4 ----------
__global__ void k_head(const float* __restrict__ h,
                       const float* __restrict__ W3, const float* __restrict__ b3,
                       const float* __restrict__ W4, const float* __restrict__ b4,
                       float* __restrict__ out, int N){
  __shared__ float sW3[32*16], sb3[16], sW4[16*2], sb4[2];
  int t = threadIdx.x;
  for (int i = t; i < 512; i += TPB) sW3[i] = W3[i];
  if (t < 16) sb3[t] = b3[t];
  if (t < 32) sW4[t] = W4[t];
  if (t < 2)  sb4[t] = b4[t];
  __syncthreads();
  int n = blockIdx.x*TPB + t;
  if (n >= N) return;
  float hin[32];
  #pragma unroll
  for (int j = 0; j < 32; j++) hin[j] = h[(size_t)n*32 + j];
  float m[16];
  #pragma unroll
  for (int o = 0; o < 16; o++){
    float a = sb3[o];
    #pragma unroll
    for (int j = 0; j < 32; j++) a += hin[j]*sW3[j*16 + o];
    m[o] = fmaxf(a, 0.f);
  }
  float o0 = sb4[0], o1 = sb4[1];
  #pragma unroll
  for (int j = 0; j < 16; j++){ o0 += m[j]*sW4[j*2]; o1 += m[j]*sW4[j*2+1]; }
  out[(size_t)n*2]     = o0;
  out[(size_t)n*2 + 1] = o1;
}

extern "C" void kernel_launch(void* const* d_in, const int* in_sizes, int n_in,
                              void* d_out, int out_size, void* d_ws, size_t ws_size,
                              hipStream_t stream){
  const float* x     = (const float*)d_in[0];
  const int*   ei    = (const int*)  d_in[1];
  const float* fc1_w = (const float*)d_in[2];
  const float* fc1_b = (const float*)d_in[3];
  const float* fc2_w = (const float*)d_in[4];
  const float* fc2_b = (const float*)d_in[5];
  const float* a_iw[4] = {(const float*)d_in[6],  (const float*)d_in[9],  (const float*)d_in[12], (const float*)d_in[15]};
  const float* a_rw[4] = {(const float*)d_in[7],  (const float*)d_in[10], (const float*)d_in[13], (const float*)d_in[16]};
  const float* a_b [4] = {(const float*)d_in[8],  (const float*)d_in[11], (const float*)d_in[14], (const float*)d_in[17]};
  const float* fc3_w = (const float*)d_in[18];
  const float* fc3_b = (const float*)d_in[19];
  const float* fc4_w = (const float*)d_in[20];
  const float* fc4_b = (const float*)d_in[21];

  const int N = in_sizes[0] / 4;
  const int E = in_sizes[1] / 2;
  const int* row = ei;
  const int* col = ei + E;

  char* p = (char*)d_ws;
  auto alloc = [&](size_t bytes)->void*{
    void* q = (void*)p;
    p += (bytes + 255) & ~size_t(255);
    return q;
  };
  float* dis    = (float*)alloc((size_t)N*4);
  int*   cnt    = (int*)  alloc((size_t)N*4);
  int*   off    = (int*)  alloc((size_t)N*4);
  int*   cursor = (int*)  alloc((size_t)N*4);
  const int nb  = (N + 1023) / 1024;
  int*   bsums  = (int*)  alloc((size_t)nb*4);
  int*   eidx   = (int*)  alloc((size_t)E*4);
  float* enorm  = (float*)alloc((size_t)E*4);
  float* h1     = (float*)alloc((size_t)N*128*4);  // fc2 out (N,128)
  float* aggH1  = (float*)alloc((size_t)N*128*4);  // L1 gather (N,128)
  float* hmid   = (float*)alloc((size_t)N*32*4);   // fc1 out
  float* h2     = (float*)alloc((size_t)N*32*4);
  float* h3     = (float*)alloc((size_t)N*32*4);
  float* aggS   = (float*)alloc((size_t)N*32*4);   // (N,32) gather for L2-4

  hipMemsetAsync(cnt, 0, (size_t)N*4, stream);
  k_deg  <<<(E+TPB-1)/TPB, TPB, 0, stream>>>(col, E, cnt);
  k_dis  <<<(N+TPB-1)/TPB, TPB, 0, stream>>>(cnt, N, dis);
  k_scan1<<<nb, TPB, 0, stream>>>(cnt, N, off, bsums);
  k_scan2<<<1, 1, 0, stream>>>(bsums, nb);
  k_scan3<<<(N+TPB-1)/TPB, TPB, 0, stream>>>(off, cursor, bsums, N);
  k_fill <<<(E+TPB-1)/TPB, TPB, 0, stream>>>(row, col, E, dis, cursor, eidx, enorm);

  const int gmm = (N + 63) / 64;
  k_fc1<<<((size_t)N*32+TPB-1)/TPB, TPB, 0, stream>>>(x, fc1_w, fc1_b, hmid, N);
  k_fc2<<<gmm, TPB, 0, stream>>>(hmid, fc2_w, fc2_b, h1, N);

  // ARMA 1 (fin=128): gather h1, then fused transform -> h2
  k_gather<128><<<(N*32 + TPB - 1)/TPB, TPB, 0, stream>>>(h1, off, cnt, eidx, enorm, aggH1, N);
  k_arma<128><<<gmm, TPB, 0, stream>>>(aggH1, h1, a_iw[0], a_rw[0], a_b[0], h2, N);

  // ARMA 2..4 (fin=32): ping-pong h2 <-> h3
  const float* hin = h2; float* hout = h3;
  for (int L = 1; L < 4; L++){
    k_gather<32><<<(N*8 + TPB - 1)/TPB, TPB, 0, stream>>>(hin, off, cnt, eidx, enorm, aggS, N);
    k_arma<32><<<gmm, TPB, 0, stream>>>(aggS, hin, a_iw[L], a_rw[L], a_b[L], hout, N);
    const float* tmp = hin; hin = hout; hout = (float*)tmp;
  }

  // after 3 swaps: L2 wrote h3, L3 wrote h2, L4 wrote h3 -> final in h3
  k_head<<<(N+TPB-1)/TPB, TPB, 0, stream>>>(h3, fc3_w, fc3_b, fc4_w, fc4_b, (float*)d_out, N);
}

// Round 5
// 757.289 us; speedup vs baseline: 2.0294x; 1.0365x over previous
//
#include <hip/hip_runtime.h>
#include <cstdint>

#define TPB 256

// ---------- degree / norm ----------
__global__ void k_deg(const int* __restrict__ col, int E, int* __restrict__ cnt){
  int e = blockIdx.x*blockDim.x + threadIdx.x;
  if (e < E) atomicAdd(&cnt[col[e]], 1);
}

__global__ void k_dis(const int* __restrict__ cnt, int N, float* __restrict__ dis){
  int n = blockIdx.x*blockDim.x + threadIdx.x;
  if (n < N){ int c = cnt[n]; dis[n] = (c > 0) ? rsqrtf((float)c) : 0.0f; }
}

// ---------- exclusive scan of cnt -> off ----------
__global__ void k_scan1(const int* __restrict__ cnt, int N, int* __restrict__ out, int* __restrict__ bsums){
  __shared__ int wsum[4];
  int t = threadIdx.x;
  int base = blockIdx.x*1024 + t*4;
  int v0 = (base+0 < N) ? cnt[base+0] : 0;
  int v1 = (base+1 < N) ? cnt[base+1] : 0;
  int v2 = (base+2 < N) ? cnt[base+2] : 0;
  int v3 = (base+3 < N) ? cnt[base+3] : 0;
  int tot = v0+v1+v2+v3;
  int lane = t & 63, wid = t >> 6;
  int x = tot;
  for (int d = 1; d < 64; d <<= 1){ int y = __shfl_up(x, d); if (lane >= d) x += y; }
  if (lane == 63) wsum[wid] = x;
  __syncthreads();
  if (t == 0){ int a = 0; for (int w = 0; w < 4; w++){ int s = wsum[w]; wsum[w] = a; a += s; } bsums[blockIdx.x] = a; }
  __syncthreads();
  int run = x - tot + wsum[wid];
  if (base+0 < N) out[base+0] = run; run += v0;
  if (base+1 < N) out[base+1] = run; run += v1;
  if (base+2 < N) out[base+2] = run; run += v2;
  if (base+3 < N) out[base+3] = run;
}

__global__ void k_scan2(int* __restrict__ bsums, int nb){
  if (blockIdx.x == 0 && threadIdx.x == 0){
    int a = 0;
    for (int i = 0; i < nb; i++){ int s = bsums[i]; bsums[i] = a; a += s; }
  }
}

__global__ void k_scan3(int* __restrict__ off, int* __restrict__ cursor, const int* __restrict__ bsums, int N){
  int i = blockIdx.x*blockDim.x + threadIdx.x;
  if (i < N){
    int v = off[i] + bsums[i >> 10];
    off[i] = v;
    cursor[i] = v;
  }
}

// ---------- CSR bucket fill ----------
__global__ void k_fill(const int* __restrict__ row, const int* __restrict__ col, int E,
                       const float* __restrict__ dis, int* __restrict__ cursor,
                       int* __restrict__ eidx, float* __restrict__ enorm){
  int e = blockIdx.x*blockDim.x + threadIdx.x;
  if (e < E){
    int r = row[e], c = col[e];
    int p = atomicAdd(&cursor[c], 1);
    eidx[p]  = r;
    enorm[p] = dis[r]*dis[c];
  }
}

// ---------- fc1: x(N,4) -> relu(x@W1+b1) (N,32) ----------
__global__ void k_fc1(const float* __restrict__ x, const float* __restrict__ W1,
                      const float* __restrict__ b1, float* __restrict__ hmid, int N){
  __shared__ float sW[128], sb[32];
  int t = threadIdx.x;
  if (t < 128) sW[t] = W1[t];
  if (t < 32)  sb[t] = b1[t];
  __syncthreads();
  int i = blockIdx.x*TPB + t;
  if (i >= N*32) return;
  int n = i >> 5, o = i & 31;
  float4 xv = *(const float4*)&x[(size_t)n*4];
  float a = sb[o] + xv.x*sW[o] + xv.y*sW[32+o] + xv.z*sW[64+o] + xv.w*sW[96+o];
  hmid[i] = fmaxf(a, 0.f);
}

// ---------- weight prep: permuted columns pos(o) so each thread's 8 outs are 2x b128 ----------
// pos(o): k=o>>5, og=(o&31)>>1, j=o&1 -> (k>>1)*64 + og*4 + (k&1)*2 + j   (m = 2k+j)
__global__ void k_wprep_arma(const float* __restrict__ iw, const float* __restrict__ rw,
                             int F, float* __restrict__ dst){
  int idx = blockIdx.x*TPB + threadIdx.x;
  if (idx >= 2*F*128) return;
  int f2 = idx >> 7, o = idx & 127;
  int k = o >> 5, og = (o & 31) >> 1, j = o & 1;
  int pos = (k >> 1)*64 + og*4 + (k & 1)*2 + j;
  float v = (f2 < F) ? iw[(k*F + f2)*32 + (o & 31)]
                     : rw[(k*F + (f2 - F))*32 + (o & 31)];
  dst[f2*128 + pos] = v;
}

__global__ void k_wprep_fc(const float* __restrict__ W, int F, float* __restrict__ dst){
  int idx = blockIdx.x*TPB + threadIdx.x;
  if (idx >= F*128) return;
  int f = idx >> 7, o = idx & 127;
  int k = o >> 5, og = (o & 31) >> 1, j = o & 1;
  int pos = (k >> 1)*64 + og*4 + (k & 1)*2 + j;
  dst[f*128 + pos] = W[f*128 + o];
}

// ---------- CSR gather: aggH[n,:] = sum_e norm * h[src,:] ----------
template<int FIN>
__global__ void k_gather(const float* __restrict__ h, const int* __restrict__ off,
                         const int* __restrict__ cnt, const int* __restrict__ eidx,
                         const float* __restrict__ enorm, float* __restrict__ aggH, int N){
  constexpr int LPN = FIN/4;
  constexpr int NPB = TPB/LPN;
  int t = threadIdx.x;
  int g = t / LPN, l = t % LPN;
  int n = blockIdx.x*NPB + g;
  if (n >= N) return;
  int s = off[n], c = cnt[n];
  float4 acc = make_float4(0.f,0.f,0.f,0.f);
  int i = 0;
  for (; i + 1 < c; i += 2){
    int   s0 = eidx[s+i],   s1 = eidx[s+i+1];
    float w0 = enorm[s+i],  w1 = enorm[s+i+1];
    float4 v0 = *(const float4*)&h[(size_t)s0*FIN + l*4];
    float4 v1 = *(const float4*)&h[(size_t)s1*FIN + l*4];
    acc.x += w0*v0.x + w1*v1.x;
    acc.y += w0*v0.y + w1*v1.y;
    acc.z += w0*v0.z + w1*v1.z;
    acc.w += w0*v0.w + w1*v1.w;
  }
  if (i < c){
    int   s0 = eidx[s+i];
    float w0 = enorm[s+i];
    float4 v0 = *(const float4*)&h[(size_t)s0*FIN + l*4];
    acc.x += w0*v0.x; acc.y += w0*v0.y; acc.z += w0*v0.z; acc.w += w0*v0.w;
  }
  *(float4*)&aggH[(size_t)n*FIN + l*4] = acc;
}

// ---------- unified GEMM: out = [srcA|srcB](N,32*T) @ Wp(32*T,128) ----------
// MODE 0: ARMA epilogue: out(N,32) = 0.25*sum_k relu(col + bias)   (stack-mean, thread-local)
// MODE 1: plain: out(N,128) = relu(col + bias)
// Block: 256 nodes x 128 outs, 256 threads, thread tile 16 nodes x 8 outs (o-pair x 4 stacks).
template<int F, int T, int TA, int MODE>
__global__ __launch_bounds__(256, 2) void k_gemm(
    const float* __restrict__ srcA, const float* __restrict__ srcB,
    const float* __restrict__ Wp, const float* __restrict__ bias,
    float* __restrict__ out, int N){
  __shared__ float sG[32*260];   // [f][node], pad 260 -> <=2-way conflicts
  __shared__ float sW[32*132];   // [f][pos], pad 132
  int t = threadIdx.x;
  int ng = t >> 4, og = t & 15;
  int n0 = blockIdx.x*256;

  float acc[16][8];
  #pragma unroll
  for (int i = 0; i < 16; i++)
    #pragma unroll
    for (int m = 0; m < 8; m++) acc[i][m] = 0.f;

  for (int tt = 0; tt < T; ++tt){
    const float* src = (tt < TA) ? srcA : srcB;
    int fb = (tt < TA) ? tt*32 : (tt - TA)*32;
    __syncthreads();
    // stage Wp tile [32][128] -> sW (b128 copies)
    #pragma unroll
    for (int j = 0; j < 4; j++){
      int q = t + j*256;
      int fr = q >> 5, c4 = (q & 31)*4;
      *(float4*)&sW[fr*132 + c4] = *(const float4*)&Wp[(tt*32 + fr)*128 + c4];
    }
    // stage G tile: 256 nodes x 32 f, transposed to [f][node]
    #pragma unroll
    for (int j = 0; j < 8; j++){
      int q = t + j*256;
      int n = q & 255, f4 = (q >> 8)*4;
      int node = n0 + n;
      float4 v = make_float4(0.f,0.f,0.f,0.f);
      if (node < N) v = *(const float4*)&src[(size_t)node*F + fb + f4];
      sG[(f4+0)*260 + n] = v.x;
      sG[(f4+1)*260 + n] = v.y;
      sG[(f4+2)*260 + n] = v.z;
      sG[(f4+3)*260 + n] = v.w;
    }
    __syncthreads();
    #pragma unroll 4
    for (int f = 0; f < 32; f++){
      float4 a0 = *(float4*)&sG[f*260 + 16*ng];
      float4 a1 = *(float4*)&sG[f*260 + 16*ng + 4];
      float4 a2 = *(float4*)&sG[f*260 + 16*ng + 8];
      float4 a3 = *(float4*)&sG[f*260 + 16*ng + 12];
      float4 w0 = *(float4*)&sW[f*132 + 4*og];
      float4 w1 = *(float4*)&sW[f*132 + 64 + 4*og];
      float av[16] = {a0.x,a0.y,a0.z,a0.w, a1.x,a1.y,a1.z,a1.w,
                      a2.x,a2.y,a2.z,a2.w, a3.x,a3.y,a3.z,a3.w};
      float wv[8]  = {w0.x,w0.y,w0.z,w0.w, w1.x,w1.y,w1.z,w1.w};
      #pragma unroll
      for (int i = 0; i < 16; i++)
        #pragma unroll
        for (int m = 0; m < 8; m++) acc[i][m] += av[i]*wv[m];
    }
  }

  // bias in permuted order: bb[m=2k+j] = bias[k*32 + 2og + j]
  float bb[8];
  #pragma unroll
  for (int m = 0; m < 8; m++) bb[m] = bias[(m >> 1)*32 + 2*og + (m & 1)];

  #pragma unroll
  for (int i = 0; i < 16; i++){
    int n = n0 + 16*ng + i;
    if (n >= N) continue;
    if (MODE == 0){
      float s0 = 0.f, s1 = 0.f;
      #pragma unroll
      for (int k = 0; k < 4; k++){
        s0 += fmaxf(acc[i][2*k]   + bb[2*k],   0.f);
        s1 += fmaxf(acc[i][2*k+1] + bb[2*k+1], 0.f);
      }
      float2 v; v.x = 0.25f*s0; v.y = 0.25f*s1;
      *(float2*)&out[(size_t)n*32 + 2*og] = v;
    } else {
      #pragma unroll
      for (int k = 0; k < 4; k++){
        float2 v;
        v.x = fmaxf(acc[i][2*k]   + bb[2*k],   0.f);
        v.y = fmaxf(acc[i][2*k+1] + bb[2*k+1], 0.f);
        *(float2*)&out[(size_t)n*128 + k*32 + 2*og] = v;
      }
    }
  }
}

// ---------- head: relu(h@W3+b3)@W4+b4 ----------
__global__ void k_head(const float* __restrict__ h,
                       const float* __restrict__ W3, const float* __restrict__ b3,
                       const float* __restrict__ W4, const float* __restrict__ b4,
                       float* __restrict__ out, int N){
  __shared__ float sW3[32*16], sb3[16], sW4[16*2], sb4[2];
  int t = threadIdx.x;
  for (int i = t; i < 512; i += TPB) sW3[i] = W3[i];
  if (t < 16) sb3[t] = b3[t];
  if (t < 32) sW4[t] = W4[t];
  if (t < 2)  sb4[t] = b4[t];
  __syncthreads();
  int n = blockIdx.x*TPB + t;
  if (n >= N) return;
  float hin[32];
  #pragma unroll
  for (int j = 0; j < 32; j++) hin[j] = h[(size_t)n*32 + j];
  float m[16];
  #pragma unroll
  for (int o = 0; o < 16; o++){
    float a = sb3[o];
    #pragma unroll
    for (int j = 0; j < 32; j++) a += hin[j]*sW3[j*16 + o];
    m[o] = fmaxf(a, 0.f);
  }
  float o0 = sb4[0], o1 = sb4[1];
  #pragma unroll
  for (int j = 0; j < 16; j++){ o0 += m[j]*sW4[j*2]; o1 += m[j]*sW4[j*2+1]; }
  out[(size_t)n*2]     = o0;
  out[(size_t)n*2 + 1] = o1;
}

extern "C" void kernel_launch(void* const* d_in, const int* in_sizes, int n_in,
                              void* d_out, int out_size, void* d_ws, size_t ws_size,
                              hipStream_t stream){
  const float* x     = (const float*)d_in[0];
  const int*   ei    = (const int*)  d_in[1];
  const float* fc1_w = (const float*)d_in[2];
  const float* fc1_b = (const float*)d_in[3];
  const float* fc2_w = (const float*)d_in[4];
  const float* fc2_b = (const float*)d_in[5];
  const float* a_iw[4] = {(const float*)d_in[6],  (const float*)d_in[9],  (const float*)d_in[12], (const float*)d_in[15]};
  const float* a_rw[4] = {(const float*)d_in[7],  (const float*)d_in[10], (const float*)d_in[13], (const float*)d_in[16]};
  const float* a_b [4] = {(const float*)d_in[8],  (const float*)d_in[11], (const float*)d_in[14], (const float*)d_in[17]};
  const float* fc3_w = (const float*)d_in[18];
  const float* fc3_b = (const float*)d_in[19];
  const float* fc4_w = (const float*)d_in[20];
  const float* fc4_b = (const float*)d_in[21];

  const int N = in_sizes[0] / 4;
  const int E = in_sizes[1] / 2;
  const int* row = ei;
  const int* col = ei + E;

  char* p = (char*)d_ws;
  auto alloc = [&](size_t bytes)->void*{
    void* q = (void*)p;
    p += (bytes + 255) & ~size_t(255);
    return q;
  };
  float* dis    = (float*)alloc((size_t)N*4);
  int*   cnt    = (int*)  alloc((size_t)N*4);
  int*   off    = (int*)  alloc((size_t)N*4);
  int*   cursor = (int*)  alloc((size_t)N*4);
  const int nb  = (N + 1023) / 1024;
  int*   bsums  = (int*)  alloc((size_t)nb*4);
  int*   eidx   = (int*)  alloc((size_t)E*4);
  float* enorm  = (float*)alloc((size_t)E*4);
  float* h1     = (float*)alloc((size_t)N*128*4);  // fc2 out (N,128)
  float* aggH1  = (float*)alloc((size_t)N*128*4);  // L1 gather (N,128)
  float* hmid   = (float*)alloc((size_t)N*32*4);
  float* h2     = (float*)alloc((size_t)N*32*4);
  float* h3     = (float*)alloc((size_t)N*32*4);
  float* aggS   = (float*)alloc((size_t)N*32*4);
  float* WpFC2  = (float*)alloc((size_t)32*128*4);
  float* Wp1    = (float*)alloc((size_t)256*128*4);
  float* Wp2    = (float*)alloc((size_t)64*128*4);
  float* Wp3    = (float*)alloc((size_t)64*128*4);
  float* Wp4    = (float*)alloc((size_t)64*128*4);
  float* WpA[4] = {Wp1, Wp2, Wp3, Wp4};

  hipMemsetAsync(cnt, 0, (size_t)N*4, stream);
  k_deg  <<<(E+TPB-1)/TPB, TPB, 0, stream>>>(col, E, cnt);
  k_dis  <<<(N+TPB-1)/TPB, TPB, 0, stream>>>(cnt, N, dis);
  k_scan1<<<nb, TPB, 0, stream>>>(cnt, N, off, bsums);
  k_scan2<<<1, 1, 0, stream>>>(bsums, nb);
  k_scan3<<<(N+TPB-1)/TPB, TPB, 0, stream>>>(off, cursor, bsums, N);
  k_fill <<<(E+TPB-1)/TPB, TPB, 0, stream>>>(row, col, E, dis, cursor, eidx, enorm);

  // weight prep (tiny)
  k_wprep_fc  <<<(32*128+TPB-1)/TPB,  TPB, 0, stream>>>(fc2_w, 32, WpFC2);
  k_wprep_arma<<<(2*128*128+TPB-1)/TPB, TPB, 0, stream>>>(a_iw[0], a_rw[0], 128, Wp1);
  for (int L = 1; L < 4; L++)
    k_wprep_arma<<<(2*32*128+TPB-1)/TPB, TPB, 0, stream>>>(a_iw[L], a_rw[L], 32, WpA[L]);

  const int gg = (N + 255) / 256;
  k_fc1<<<((size_t)N*32+TPB-1)/TPB, TPB, 0, stream>>>(x, fc1_w, fc1_b, hmid, N);
  k_gemm<32,1,1,1><<<gg, TPB, 0, stream>>>(hmid, hmid, WpFC2, fc2_b, h1, N);

  // ARMA 1 (fin=128): gather h1, unified GEMM -> h2
  k_gather<128><<<(N*32 + TPB - 1)/TPB, TPB, 0, stream>>>(h1, off, cnt, eidx, enorm, aggH1, N);
  k_gemm<128,8,4,0><<<gg, TPB, 0, stream>>>(aggH1, h1, Wp1, a_b[0], h2, N);

  // ARMA 2..4 (fin=32): ping-pong h2 <-> h3
  const float* hin = h2; float* hout = h3;
  for (int L = 1; L < 4; L++){
    k_gather<32><<<(N*8 + TPB - 1)/TPB, TPB, 0, stream>>>(hin, off, cnt, eidx, enorm, aggS, N);
    k_gemm<32,2,1,0><<<gg, TPB, 0, stream>>>(aggS, hin, WpA[L], a_b[L], hout, N);
    const float* tmp = hin; hin = hout; hout = (float*)tmp;
  }

  // after 3 swaps: final ARMA output in h3
  k_head<<<(N+TPB-1)/TPB, TPB, 0, stream>>>(h3, fc3_w, fc3_b, fc4_w, fc4_b, (float*)d_out, N);
}

// Round 7
// 703.542 us; speedup vs baseline: 2.1844x; 1.0764x over previous
//
#include <hip/hip_runtime.h>
#include <cstdint>

#define TPB 256

// ---------- degree ----------
__global__ void k_deg(const int* __restrict__ col, int E, int* __restrict__ cnt){
  int e = blockIdx.x*blockDim.x + threadIdx.x;
  if (e < E) atomicAdd(&cnt[col[e]], 1);
}

// ---------- exclusive scan of cnt -> off, fused deg^-1/2 ----------
__global__ void k_scan1(const int* __restrict__ cnt, int N, int* __restrict__ out,
                        int* __restrict__ bsums, float* __restrict__ dis){
  __shared__ int wsum[4];
  int t = threadIdx.x;
  int base = blockIdx.x*1024 + t*4;
  int v0 = (base+0 < N) ? cnt[base+0] : 0;
  int v1 = (base+1 < N) ? cnt[base+1] : 0;
  int v2 = (base+2 < N) ? cnt[base+2] : 0;
  int v3 = (base+3 < N) ? cnt[base+3] : 0;
  if (base+0 < N) dis[base+0] = (v0 > 0) ? rsqrtf((float)v0) : 0.f;
  if (base+1 < N) dis[base+1] = (v1 > 0) ? rsqrtf((float)v1) : 0.f;
  if (base+2 < N) dis[base+2] = (v2 > 0) ? rsqrtf((float)v2) : 0.f;
  if (base+3 < N) dis[base+3] = (v3 > 0) ? rsqrtf((float)v3) : 0.f;
  int tot = v0+v1+v2+v3;
  int lane = t & 63, wid = t >> 6;
  int x = tot;
  for (int d = 1; d < 64; d <<= 1){ int y = __shfl_up(x, d); if (lane >= d) x += y; }
  if (lane == 63) wsum[wid] = x;
  __syncthreads();
  if (t == 0){ int a = 0; for (int w = 0; w < 4; w++){ int s = wsum[w]; wsum[w] = a; a += s; } bsums[blockIdx.x] = a; }
  __syncthreads();
  int run = x - tot + wsum[wid];
  if (base+0 < N) out[base+0] = run; run += v0;
  if (base+1 < N) out[base+1] = run; run += v1;
  if (base+2 < N) out[base+2] = run; run += v2;
  if (base+3 < N) out[base+3] = run;
}

__global__ void k_scan2(int* __restrict__ bsums, int nb){
  if (blockIdx.x == 0 && threadIdx.x == 0){
    int a = 0;
    for (int i = 0; i < nb; i++){ int s = bsums[i]; bsums[i] = a; a += s; }
  }
}

__global__ void k_scan3(int* __restrict__ off, int* __restrict__ cursor, const int* __restrict__ bsums, int N){
  int i = blockIdx.x*blockDim.x + threadIdx.x;
  if (i < N){
    int v = off[i] + bsums[i >> 10];
    off[i] = v;
    cursor[i] = v;
  }
}

// ---------- CSR bucket fill: single 8B packed scatter per edge ----------
__global__ void k_fill(const int* __restrict__ row, const int* __restrict__ col, int E,
                       const float* __restrict__ dis, int* __restrict__ cursor,
                       int2* __restrict__ edata){
  int e = blockIdx.x*blockDim.x + threadIdx.x;
  if (e < E){
    int r = row[e], c = col[e];
    int p = atomicAdd(&cursor[c], 1);
    edata[p] = make_int2(r, __float_as_int(dis[r]*dis[c]));
  }
}

// ---------- fc1: x(N,4) -> relu(x@W1+b1) (N,32) ----------
__global__ void k_fc1(const float* __restrict__ x, const float* __restrict__ W1,
                      const float* __restrict__ b1, float* __restrict__ hmid, int N){
  __shared__ float sW[128], sb[32];
  int t = threadIdx.x;
  if (t < 128) sW[t] = W1[t];
  if (t < 32)  sb[t] = b1[t];
  __syncthreads();
  int i = blockIdx.x*TPB + t;
  if (i >= N*32) return;
  int n = i >> 5, o = i & 31;
  float4 xv = *(const float4*)&x[(size_t)n*4];
  float a = sb[o] + xv.x*sW[o] + xv.y*sW[32+o] + xv.z*sW[64+o] + xv.w*sW[96+o];
  hmid[i] = fmaxf(a, 0.f);
}

// ---------- weight prep: permuted columns pos(o) so each thread's 8 outs are 2x b128 ----------
// pos(o): k=o>>5, og=(o&31)>>1, j=o&1 -> (k>>1)*64 + og*4 + (k&1)*2 + j   (m = 2k+j)
__global__ void k_wprep_arma(const float* __restrict__ iw, const float* __restrict__ rw,
                             int F, float* __restrict__ dst){
  int idx = blockIdx.x*TPB + threadIdx.x;
  if (idx >= 2*F*128) return;
  int f2 = idx >> 7, o = idx & 127;
  int k = o >> 5, og = (o & 31) >> 1, j = o & 1;
  int pos = (k >> 1)*64 + og*4 + (k & 1)*2 + j;
  float v = (f2 < F) ? iw[(k*F + f2)*32 + (o & 31)]
                     : rw[(k*F + (f2 - F))*32 + (o & 31)];
  dst[f2*128 + pos] = v;
}

__global__ void k_wprep_fc(const float* __restrict__ W, int F, float* __restrict__ dst){
  int idx = blockIdx.x*TPB + threadIdx.x;
  if (idx >= F*128) return;
  int f = idx >> 7, o = idx & 127;
  int k = o >> 5, og = (o & 31) >> 1, j = o & 1;
  int pos = (k >> 1)*64 + og*4 + (k & 1)*2 + j;
  dst[f*128 + pos] = W[f*128 + o];
}

// ---------- CSR gather: aggH[n,:] = sum_e norm * h[src,:] (ILP-4) ----------
template<int FIN>
__global__ void k_gather(const float* __restrict__ h, const int* __restrict__ off,
                         const int* __restrict__ cnt, const int2* __restrict__ edata,
                         float* __restrict__ aggH, int N){
  constexpr int LPN = FIN/4;
  constexpr int NPB = TPB/LPN;
  int t = threadIdx.x;
  int g = t / LPN, l = t % LPN;
  int n = blockIdx.x*NPB + g;
  if (n >= N) return;
  int s = off[n], c = cnt[n];
  float4 accA = make_float4(0.f,0.f,0.f,0.f);
  float4 accB = make_float4(0.f,0.f,0.f,0.f);
  int i = 0;
  for (; i + 3 < c; i += 4){
    int2 e0 = edata[s+i],   e1 = edata[s+i+1];
    int2 e2 = edata[s+i+2], e3 = edata[s+i+3];
    float w0 = __int_as_float(e0.y), w1 = __int_as_float(e1.y);
    float w2 = __int_as_float(e2.y), w3 = __int_as_float(e3.y);
    float4 v0 = *(const float4*)&h[(size_t)e0.x*FIN + l*4];
    float4 v1 = *(const float4*)&h[(size_t)e1.x*FIN + l*4];
    float4 v2 = *(const float4*)&h[(size_t)e2.x*FIN + l*4];
    float4 v3 = *(const float4*)&h[(size_t)e3.x*FIN + l*4];
    accA.x += w0*v0.x + w1*v1.x;  accA.y += w0*v0.y + w1*v1.y;
    accA.z += w0*v0.z + w1*v1.z;  accA.w += w0*v0.w + w1*v1.w;
    accB.x += w2*v2.x + w3*v3.x;  accB.y += w2*v2.y + w3*v3.y;
    accB.z += w2*v2.z + w3*v3.z;  accB.w += w2*v2.w + w3*v3.w;
  }
  for (; i < c; i++){
    int2 e0 = edata[s+i];
    float w0 = __int_as_float(e0.y);
    float4 v0 = *(const float4*)&h[(size_t)e0.x*FIN + l*4];
    accA.x += w0*v0.x; accA.y += w0*v0.y; accA.z += w0*v0.z; accA.w += w0*v0.w;
  }
  accA.x += accB.x; accA.y += accB.y; accA.z += accB.z; accA.w += accB.w;
  *(float4*)&aggH[(size_t)n*FIN + l*4] = accA;
}

// ---------- unified GEMM: out = [srcA|srcB](N,32*T) @ Wp(32*T,128) ----------
// MODE 0: ARMA epilogue: out(N,32) = 0.25*sum_k relu(col + bias)
// MODE 1: plain: out(N,128) = relu(col + bias)
template<int F, int T, int TA, int MODE>
__global__ __launch_bounds__(256, 2) void k_gemm(
    const float* __restrict__ srcA, const float* __restrict__ srcB,
    const float* __restrict__ Wp, const float* __restrict__ bias,
    float* __restrict__ out, int N){
  __shared__ float sG[32*260];
  __shared__ float sW[32*132];
  int t = threadIdx.x;
  int ng = t >> 4, og = t & 15;
  int n0 = blockIdx.x*256;

  float acc[16][8];
  #pragma unroll
  for (int i = 0; i < 16; i++)
    #pragma unroll
    for (int m = 0; m < 8; m++) acc[i][m] = 0.f;

  for (int tt = 0; tt < T; ++tt){
    const float* src = (tt < TA) ? srcA : srcB;
    int fb = (tt < TA) ? tt*32 : (tt - TA)*32;
    __syncthreads();
    #pragma unroll
    for (int j = 0; j < 4; j++){
      int q = t + j*256;
      int fr = q >> 5, c4 = (q & 31)*4;
      *(float4*)&sW[fr*132 + c4] = *(const float4*)&Wp[(tt*32 + fr)*128 + c4];
    }
    #pragma unroll
    for (int j = 0; j < 8; j++){
      int q = t + j*256;
      int n = q & 255, f4 = (q >> 8)*4;
      int node = n0 + n;
      float4 v = make_float4(0.f,0.f,0.f,0.f);
      if (node < N) v = *(const float4*)&src[(size_t)node*F + fb + f4];
      sG[(f4+0)*260 + n] = v.x;
      sG[(f4+1)*260 + n] = v.y;
      sG[(f4+2)*260 + n] = v.z;
      sG[(f4+3)*260 + n] = v.w;
    }
    __syncthreads();
    #pragma unroll 4
    for (int f = 0; f < 32; f++){
      float4 a0 = *(float4*)&sG[f*260 + 16*ng];
      float4 a1 = *(float4*)&sG[f*260 + 16*ng + 4];
      float4 a2 = *(float4*)&sG[f*260 + 16*ng + 8];
      float4 a3 = *(float4*)&sG[f*260 + 16*ng + 12];
      float4 w0 = *(float4*)&sW[f*132 + 4*og];
      float4 w1 = *(float4*)&sW[f*132 + 64 + 4*og];
      float av[16] = {a0.x,a0.y,a0.z,a0.w, a1.x,a1.y,a1.z,a1.w,
                      a2.x,a2.y,a2.z,a2.w, a3.x,a3.y,a3.z,a3.w};
      float wv[8]  = {w0.x,w0.y,w0.z,w0.w, w1.x,w1.y,w1.z,w1.w};
      #pragma unroll
      for (int i = 0; i < 16; i++)
        #pragma unroll
        for (int m = 0; m < 8; m++) acc[i][m] += av[i]*wv[m];
    }
  }

  float bb[8];
  #pragma unroll
  for (int m = 0; m < 8; m++) bb[m] = bias[(m >> 1)*32 + 2*og + (m & 1)];

  #pragma unroll
  for (int i = 0; i < 16; i++){
    int n = n0 + 16*ng + i;
    if (n >= N) continue;
    if (MODE == 0){
      float s0 = 0.f, s1 = 0.f;
      #pragma unroll
      for (int k = 0; k < 4; k++){
        s0 += fmaxf(acc[i][2*k]   + bb[2*k],   0.f);
        s1 += fmaxf(acc[i][2*k+1] + bb[2*k+1], 0.f);
      }
      float2 v; v.x = 0.25f*s0; v.y = 0.25f*s1;
      *(float2*)&out[(size_t)n*32 + 2*og] = v;
    } else {
      #pragma unroll
      for (int k = 0; k < 4; k++){
        float2 v;
        v.x = fmaxf(acc[i][2*k]   + bb[2*k],   0.f);
        v.y = fmaxf(acc[i][2*k+1] + bb[2*k+1], 0.f);
        *(float2*)&out[(size_t)n*128 + k*32 + 2*og] = v;
      }
    }
  }
}

// ---------- head: relu(h@W3+b3)@W4+b4 ----------
__global__ void k_head(const float* __restrict__ h,
                       const float* __restrict__ W3, const float* __restrict__ b3,
                       const float* __restrict__ W4, const float* __restrict__ b4,
                       float* __restrict__ out, int N){
  __shared__ float sW3[32*16], sb3[16], sW4[16*2], sb4[2];
  int t = threadIdx.x;
  for (int i = t; i < 512; i += TPB) sW3[i] = W3[i];
  if (t < 16) sb3[t] = b3[t];
  if (t < 32) sW4[t] = W4[t];
  if (t < 2)  sb4[t] = b4[t];
  __syncthreads();
  int n = blockIdx.x*TPB + t;
  if (n >= N) return;
  float hin[32];
  #pragma unroll
  for (int j = 0; j < 32; j++) hin[j] = h[(size_t)n*32 + j];
  float m[16];
  #pragma unroll
  for (int o = 0; o < 16; o++){
    float a = sb3[o];
    #pragma unroll
    for (int j = 0; j < 32; j++) a += hin[j]*sW3[j*16 + o];
    m[o] = fmaxf(a, 0.f);
  }
  float o0 = sb4[0], o1 = sb4[1];
  #pragma unroll
  for (int j = 0; j < 16; j++){ o0 += m[j]*sW4[j*2]; o1 += m[j]*sW4[j*2+1]; }
  out[(size_t)n*2]     = o0;
  out[(size_t)n*2 + 1] = o1;
}

extern "C" void kernel_launch(void* const* d_in, const int* in_sizes, int n_in,
                              void* d_out, int out_size, void* d_ws, size_t ws_size,
                              hipStream_t stream){
  const float* x     = (const float*)d_in[0];
  const int*   ei    = (const int*)  d_in[1];
  const float* fc1_w = (const float*)d_in[2];
  const float* fc1_b = (const float*)d_in[3];
  const float* fc2_w = (const float*)d_in[4];
  const float* fc2_b = (const float*)d_in[5];
  const float* a_iw[4] = {(const float*)d_in[6],  (const float*)d_in[9],  (const float*)d_in[12], (const float*)d_in[15]};
  const float* a_rw[4] = {(const float*)d_in[7],  (const float*)d_in[10], (const float*)d_in[13], (const float*)d_in[16]};
  const float* a_b [4] = {(const float*)d_in[8],  (const float*)d_in[11], (const float*)d_in[14], (const float*)d_in[17]};
  const float* fc3_w = (const float*)d_in[18];
  const float* fc3_b = (const float*)d_in[19];
  const float* fc4_w = (const float*)d_in[20];
  const float* fc4_b = (const float*)d_in[21];

  const int N = in_sizes[0] / 4;
  const int E = in_sizes[1] / 2;
  const int* row = ei;
  const int* col = ei + E;

  char* p = (char*)d_ws;
  auto alloc = [&](size_t bytes)->void*{
    void* q = (void*)p;
    p += (bytes + 255) & ~size_t(255);
    return q;
  };
  float* dis    = (float*)alloc((size_t)N*4);
  int*   cnt    = (int*)  alloc((size_t)N*4);
  int*   off    = (int*)  alloc((size_t)N*4);
  int*   cursor = (int*)  alloc((size_t)N*4);
  const int nb  = (N + 1023) / 1024;
  int*   bsums  = (int*)  alloc((size_t)nb*4);
  int2*  edata  = (int2*) alloc((size_t)E*8);
  float* h1     = (float*)alloc((size_t)N*128*4);
  float* aggH1  = (float*)alloc((size_t)N*128*4);
  float* hmid   = (float*)alloc((size_t)N*32*4);
  float* h2     = (float*)alloc((size_t)N*32*4);
  float* h3     = (float*)alloc((size_t)N*32*4);
  float* aggS   = (float*)alloc((size_t)N*32*4);
  float* WpFC2  = (float*)alloc((size_t)32*128*4);
  float* Wp1    = (float*)alloc((size_t)256*128*4);
  float* Wp2    = (float*)alloc((size_t)64*128*4);
  float* Wp3    = (float*)alloc((size_t)64*128*4);
  float* Wp4    = (float*)alloc((size_t)64*128*4);
  float* WpA[4] = {Wp1, Wp2, Wp3, Wp4};

  hipMemsetAsync(cnt, 0, (size_t)N*4, stream);
  k_deg  <<<(E+TPB-1)/TPB, TPB, 0, stream>>>(col, E, cnt);
  k_scan1<<<nb, TPB, 0, stream>>>(cnt, N, off, bsums, dis);
  k_scan2<<<1, 1, 0, stream>>>(bsums, nb);
  k_scan3<<<(N+TPB-1)/TPB, TPB, 0, stream>>>(off, cursor, bsums, N);
  k_fill <<<(E+TPB-1)/TPB, TPB, 0, stream>>>(row, col, E, dis, cursor, edata);

  // weight prep (tiny)
  k_wprep_fc  <<<(32*128+TPB-1)/TPB,  TPB, 0, stream>>>(fc2_w, 32, WpFC2);
  k_wprep_arma<<<(2*128*128+TPB-1)/TPB, TPB, 0, stream>>>(a_iw[0], a_rw[0], 128, Wp1);
  for (int L = 1; L < 4; L++)
    k_wprep_arma<<<(2*32*128+TPB-1)/TPB, TPB, 0, stream>>>(a_iw[L], a_rw[L], 32, WpA[L]);

  const int gg = (N + 255) / 256;
  k_fc1<<<((size_t)N*32+TPB-1)/TPB, TPB, 0, stream>>>(x, fc1_w, fc1_b, hmid, N);
  k_gemm<32,1,1,1><<<gg, TPB, 0, stream>>>(hmid, hmid, WpFC2, fc2_b, h1, N);

  // ARMA 1 (fin=128): gather h1, unified GEMM -> h2
  k_gather<128><<<(N*32 + TPB - 1)/TPB, TPB, 0, stream>>>(h1, off, cnt, edata, aggH1, N);
  k_gemm<128,8,4,0><<<gg, TPB, 0, stream>>>(aggH1, h1, Wp1, a_b[0], h2, N);

  // ARMA 2..4 (fin=32): ping-pong h2 <-> h3
  const float* hin = h2; float* hout = h3;
  for (int L = 1; L < 4; L++){
    k_gather<32><<<(N*8 + TPB - 1)/TPB, TPB, 0, stream>>>(hin, off, cnt, edata, aggS, N);
    k_gemm<32,2,1,0><<<gg, TPB, 0, stream>>>(aggS, hin, WpA[L], a_b[L], hout, N);
    const float* tmp = hin; hin = hout; hout = (float*)tmp;
  }

  // after 3 swaps: final ARMA output in h3
  k_head<<<(N+TPB-1)/TPB, TPB, 0, stream>>>(h3, fc3_w, fc3_b, fc4_w, fc4_b, (float*)d_out, N);
}

// Round 9
// 700.926 us; speedup vs baseline: 2.1926x; 1.0037x over previous
//
#include <hip/hip_runtime.h>
#include <cstdint>

#define TPB 256

typedef unsigned short ushort_t;

__device__ __forceinline__ ushort_t bf16rne(float f){
  unsigned u = __float_as_uint(f);
  u += 0x7FFFu + ((u >> 16) & 1u);
  return (ushort_t)(u >> 16);
}
__device__ __forceinline__ float bf16f(ushort_t u){
  return __uint_as_float(((unsigned)u) << 16);
}

// ---------- degree ----------
__global__ void k_deg(const int* __restrict__ col, int E, int* __restrict__ cnt){
  int e = blockIdx.x*blockDim.x + threadIdx.x;
  if (e < E) atomicAdd(&cnt[col[e]], 1);
}

// ---------- exclusive scan of cnt -> off, fused deg^-1/2 ----------
__global__ void k_scan1(const int* __restrict__ cnt, int N, int* __restrict__ out,
                        int* __restrict__ bsums, float* __restrict__ dis){
  __shared__ int wsum[4];
  int t = threadIdx.x;
  int base = blockIdx.x*1024 + t*4;
  int v0 = (base+0 < N) ? cnt[base+0] : 0;
  int v1 = (base+1 < N) ? cnt[base+1] : 0;
  int v2 = (base+2 < N) ? cnt[base+2] : 0;
  int v3 = (base+3 < N) ? cnt[base+3] : 0;
  if (base+0 < N) dis[base+0] = (v0 > 0) ? rsqrtf((float)v0) : 0.f;
  if (base+1 < N) dis[base+1] = (v1 > 0) ? rsqrtf((float)v1) : 0.f;
  if (base+2 < N) dis[base+2] = (v2 > 0) ? rsqrtf((float)v2) : 0.f;
  if (base+3 < N) dis[base+3] = (v3 > 0) ? rsqrtf((float)v3) : 0.f;
  int tot = v0+v1+v2+v3;
  int lane = t & 63, wid = t >> 6;
  int x = tot;
  for (int d = 1; d < 64; d <<= 1){ int y = __shfl_up(x, d); if (lane >= d) x += y; }
  if (lane == 63) wsum[wid] = x;
  __syncthreads();
  if (t == 0){ int a = 0; for (int w = 0; w < 4; w++){ int s = wsum[w]; wsum[w] = a; a += s; } bsums[blockIdx.x] = a; }
  __syncthreads();
  int run = x - tot + wsum[wid];
  if (base+0 < N) out[base+0] = run; run += v0;
  if (base+1 < N) out[base+1] = run; run += v1;
  if (base+2 < N) out[base+2] = run; run += v2;
  if (base+3 < N) out[base+3] = run;
}

__global__ void k_scan2(int* __restrict__ bsums, int nb){
  if (blockIdx.x == 0 && threadIdx.x == 0){
    int a = 0;
    for (int i = 0; i < nb; i++){ int s = bsums[i]; bsums[i] = a; a += s; }
  }
}

__global__ void k_scan3(int* __restrict__ off, int* __restrict__ cursor, const int* __restrict__ bsums, int N){
  int i = blockIdx.x*blockDim.x + threadIdx.x;
  if (i < N){
    int v = off[i] + bsums[i >> 10];
    off[i] = v;
    cursor[i] = v;
  }
}

// ---------- CSR bucket fill: single 4B scatter per edge (src only) ----------
__global__ void k_fill(const int* __restrict__ row, const int* __restrict__ col, int E,
                       int* __restrict__ cursor, int* __restrict__ esrc){
  int e = blockIdx.x*blockDim.x + threadIdx.x;
  if (e < E){
    int p = atomicAdd(&cursor[col[e]], 1);
    esrc[p] = row[e];
  }
}

// ---------- fc1: x(N,4) -> relu(x@W1+b1) (N,32) ----------
__global__ void k_fc1(const float* __restrict__ x, const float* __restrict__ W1,
                      const float* __restrict__ b1, float* __restrict__ hmid, int N){
  __shared__ float sW[128], sb[32];
  int t = threadIdx.x;
  if (t < 128) sW[t] = W1[t];
  if (t < 32)  sb[t] = b1[t];
  __syncthreads();
  int i = blockIdx.x*TPB + t;
  if (i >= N*32) return;
  int n = i >> 5, o = i & 31;
  float4 xv = *(const float4*)&x[(size_t)n*4];
  float a = sb[o] + xv.x*sW[o] + xv.y*sW[32+o] + xv.z*sW[64+o] + xv.w*sW[96+o];
  hmid[i] = fmaxf(a, 0.f);
}

// ---------- weight prep: permuted columns pos(o) ----------
// pos(o): k=o>>5, og=(o&31)>>1, j=o&1 -> (k>>1)*64 + og*4 + (k&1)*2 + j   (m = 2k+j)
__global__ void k_wprep_arma(const float* __restrict__ iw, const float* __restrict__ rw,
                             int F, float* __restrict__ dst){
  int idx = blockIdx.x*TPB + threadIdx.x;
  if (idx >= 2*F*128) return;
  int f2 = idx >> 7, o = idx & 127;
  int k = o >> 5, og = (o & 31) >> 1, j = o & 1;
  int pos = (k >> 1)*64 + og*4 + (k & 1)*2 + j;
  float v = (f2 < F) ? iw[(k*F + f2)*32 + (o & 31)]
                     : rw[(k*F + (f2 - F))*32 + (o & 31)];
  dst[f2*128 + pos] = v;
}

__global__ void k_wprep_fc(const float* __restrict__ W, int F, float* __restrict__ dst){
  int idx = blockIdx.x*TPB + threadIdx.x;
  if (idx >= F*128) return;
  int f = idx >> 7, o = idx & 127;
  int k = o >> 5, og = (o & 31) >> 1, j = o & 1;
  int pos = (k >> 1)*64 + og*4 + (k & 1)*2 + j;
  dst[f*128 + pos] = W[f*128 + o];
}

// ---------- L1 gather (bf16 table, 128 cols): aggH[n,:] = dis[n] * sum_e dis[src]*hb[src,:] ----------
__global__ void k_gather16(const ushort_t* __restrict__ hb, const int* __restrict__ off,
                           const int* __restrict__ cnt, const int* __restrict__ esrc,
                           const float* __restrict__ dis, float* __restrict__ aggH, int N){
  int t = threadIdx.x;
  int g = t >> 5, l = t & 31;            // 32 lanes/node, 4 bf16 cols each
  int n = blockIdx.x*8 + g;
  if (n >= N) return;
  int s = off[n], c = cnt[n];
  float4 accA = make_float4(0.f,0.f,0.f,0.f);
  float4 accB = make_float4(0.f,0.f,0.f,0.f);
  int i = 0;
  for (; i + 3 < c; i += 4){
    int s0 = esrc[s+i], s1 = esrc[s+i+1], s2 = esrc[s+i+2], s3 = esrc[s+i+3];
    float w0 = dis[s0], w1 = dis[s1], w2 = dis[s2], w3 = dis[s3];
    ushort4 u0 = *(const ushort4*)&hb[(size_t)s0*128 + 4*l];
    ushort4 u1 = *(const ushort4*)&hb[(size_t)s1*128 + 4*l];
    ushort4 u2 = *(const ushort4*)&hb[(size_t)s2*128 + 4*l];
    ushort4 u3 = *(const ushort4*)&hb[(size_t)s3*128 + 4*l];
    accA.x += w0*bf16f(u0.x) + w1*bf16f(u1.x);
    accA.y += w0*bf16f(u0.y) + w1*bf16f(u1.y);
    accA.z += w0*bf16f(u0.z) + w1*bf16f(u1.z);
    accA.w += w0*bf16f(u0.w) + w1*bf16f(u1.w);
    accB.x += w2*bf16f(u2.x) + w3*bf16f(u3.x);
    accB.y += w2*bf16f(u2.y) + w3*bf16f(u3.y);
    accB.z += w2*bf16f(u2.z) + w3*bf16f(u3.z);
    accB.w += w2*bf16f(u2.w) + w3*bf16f(u3.w);
  }
  for (; i < c; i++){
    int s0 = esrc[s+i];
    float w0 = dis[s0];
    ushort4 u0 = *(const ushort4*)&hb[(size_t)s0*128 + 4*l];
    accA.x += w0*bf16f(u0.x); accA.y += w0*bf16f(u0.y);
    accA.z += w0*bf16f(u0.z); accA.w += w0*bf16f(u0.w);
  }
  float wn = dis[n];
  float4 r;
  r.x = wn*(accA.x + accB.x); r.y = wn*(accA.y + accB.y);
  r.z = wn*(accA.z + accB.z); r.w = wn*(accA.w + accB.w);
  *(float4*)&aggH[(size_t)n*128 + 4*l] = r;
}

// ---------- small gather (fp32 table, 32 cols) ----------
__global__ void k_gather32(const float* __restrict__ h, const int* __restrict__ off,
                           const int* __restrict__ cnt, const int* __restrict__ esrc,
                           const float* __restrict__ dis, float* __restrict__ agg, int N){
  int t = threadIdx.x;
  int g = t >> 3, l = t & 7;             // 8 lanes/node, float4 each
  int n = blockIdx.x*32 + g;
  if (n >= N) return;
  int s = off[n], c = cnt[n];
  float4 accA = make_float4(0.f,0.f,0.f,0.f);
  float4 accB = make_float4(0.f,0.f,0.f,0.f);
  int i = 0;
  for (; i + 3 < c; i += 4){
    int s0 = esrc[s+i], s1 = esrc[s+i+1], s2 = esrc[s+i+2], s3 = esrc[s+i+3];
    float w0 = dis[s0], w1 = dis[s1], w2 = dis[s2], w3 = dis[s3];
    float4 v0 = *(const float4*)&h[(size_t)s0*32 + 4*l];
    float4 v1 = *(const float4*)&h[(size_t)s1*32 + 4*l];
    float4 v2 = *(const float4*)&h[(size_t)s2*32 + 4*l];
    float4 v3 = *(const float4*)&h[(size_t)s3*32 + 4*l];
    accA.x += w0*v0.x + w1*v1.x;  accA.y += w0*v0.y + w1*v1.y;
    accA.z += w0*v0.z + w1*v1.z;  accA.w += w0*v0.w + w1*v1.w;
    accB.x += w2*v2.x + w3*v3.x;  accB.y += w2*v2.y + w3*v3.y;
    accB.z += w2*v2.z + w3*v3.z;  accB.w += w2*v2.w + w3*v3.w;
  }
  for (; i < c; i++){
    int s0 = esrc[s+i];
    float w0 = dis[s0];
    float4 v0 = *(const float4*)&h[(size_t)s0*32 + 4*l];
    accA.x += w0*v0.x; accA.y += w0*v0.y; accA.z += w0*v0.z; accA.w += w0*v0.w;
  }
  float wn = dis[n];
  float4 r;
  r.x = wn*(accA.x + accB.x); r.y = wn*(accA.y + accB.y);
  r.z = wn*(accA.z + accB.z); r.w = wn*(accA.w + accB.w);
  *(float4*)&agg[(size_t)n*32 + 4*l] = r;
}

// ---------- unified GEMM: out = [srcA|srcB](N,32*T) @ Wp(32*T,128) ----------
// MODE 0: ARMA epilogue: out(N,32) = 0.25*sum_k relu(col + bias)
// MODE 1: plain: out(N,128) = relu(col + bias)
// MODE 2: plain + bf16 copy to out2
template<int F, int T, int TA, int MODE>
__global__ __launch_bounds__(256, 2) void k_gemm(
    const float* __restrict__ srcA, const float* __restrict__ srcB,
    const float* __restrict__ Wp, const float* __restrict__ bias,
    float* __restrict__ out, ushort_t* __restrict__ out2, int N){
  __shared__ float sG[32*260];
  __shared__ float sW[32*132];
  int t = threadIdx.x;
  int ng = t >> 4, og = t & 15;
  int n0 = blockIdx.x*256;

  float acc[16][8];
  #pragma unroll
  for (int i = 0; i < 16; i++)
    #pragma unroll
    for (int m = 0; m < 8; m++) acc[i][m] = 0.f;

  for (int tt = 0; tt < T; ++tt){
    const float* src = (tt < TA) ? srcA : srcB;
    int fb = (tt < TA) ? tt*32 : (tt - TA)*32;
    __syncthreads();
    #pragma unroll
    for (int j = 0; j < 4; j++){
      int q = t + j*256;
      int fr = q >> 5, c4 = (q & 31)*4;
      *(float4*)&sW[fr*132 + c4] = *(const float4*)&Wp[(tt*32 + fr)*128 + c4];
    }
    #pragma unroll
    for (int j = 0; j < 8; j++){
      int q = t + j*256;
      int n = q & 255, f4 = (q >> 8)*4;
      int node = n0 + n;
      float4 v = make_float4(0.f,0.f,0.f,0.f);
      if (node < N) v = *(const float4*)&src[(size_t)node*F + fb + f4];
      sG[(f4+0)*260 + n] = v.x;
      sG[(f4+1)*260 + n] = v.y;
      sG[(f4+2)*260 + n] = v.z;
      sG[(f4+3)*260 + n] = v.w;
    }
    __syncthreads();
    #pragma unroll 4
    for (int f = 0; f < 32; f++){
      float4 a0 = *(float4*)&sG[f*260 + 16*ng];
      float4 a1 = *(float4*)&sG[f*260 + 16*ng + 4];
      float4 a2 = *(float4*)&sG[f*260 + 16*ng + 8];
      float4 a3 = *(float4*)&sG[f*260 + 16*ng + 12];
      float4 w0 = *(float4*)&sW[f*132 + 4*og];
      float4 w1 = *(float4*)&sW[f*132 + 64 + 4*og];
      float av[16] = {a0.x,a0.y,a0.z,a0.w, a1.x,a1.y,a1.z,a1.w,
                      a2.x,a2.y,a2.z,a2.w, a3.x,a3.y,a3.z,a3.w};
      float wv[8]  = {w0.x,w0.y,w0.z,w0.w, w1.x,w1.y,w1.z,w1.w};
      #pragma unroll
      for (int i = 0; i < 16; i++)
        #pragma unroll
        for (int m = 0; m < 8; m++) acc[i][m] += av[i]*wv[m];
    }
  }

  float bb[8];
  #pragma unroll
  for (int m = 0; m < 8; m++) bb[m] = bias[(m >> 1)*32 + 2*og + (m & 1)];

  #pragma unroll
  for (int i = 0; i < 16; i++){
    int n = n0 + 16*ng + i;
    if (n >= N) continue;
    if (MODE == 0){
      float s0 = 0.f, s1 = 0.f;
      #pragma unroll
      for (int k = 0; k < 4; k++){
        s0 += fmaxf(acc[i][2*k]   + bb[2*k],   0.f);
        s1 += fmaxf(acc[i][2*k+1] + bb[2*k+1], 0.f);
      }
      float2 v; v.x = 0.25f*s0; v.y = 0.25f*s1;
      *(float2*)&out[(size_t)n*32 + 2*og] = v;
    } else {
      #pragma unroll
      for (int k = 0; k < 4; k++){
        float2 v;
        v.x = fmaxf(acc[i][2*k]   + bb[2*k],   0.f);
        v.y = fmaxf(acc[i][2*k+1] + bb[2*k+1], 0.f);
        *(float2*)&out[(size_t)n*128 + k*32 + 2*og] = v;
        if (MODE == 2){
          ushort2 u; u.x = bf16rne(v.x); u.y = bf16rne(v.y);
          *(ushort2*)&out2[(size_t)n*128 + k*32 + 2*og] = u;
        }
      }
    }
  }
}

// ---------- head: relu(h@W3+b3)@W4+b4 ----------
__global__ void k_head(const float* __restrict__ h,
                       const float* __restrict__ W3, const float* __restrict__ b3,
                       const float* __restrict__ W4, const float* __restrict__ b4,
                       float* __restrict__ out, int N){
  __shared__ float sW3[32*16], sb3[16], sW4[16*2], sb4[2];
  int t = threadIdx.x;
  for (int i = t; i < 512; i += TPB) sW3[i] = W3[i];
  if (t < 16) sb3[t] = b3[t];
  if (t < 32) sW4[t] = W4[t];
  if (t < 2)  sb4[t] = b4[t];
  __syncthreads();
  int n = blockIdx.x*TPB + t;
  if (n >= N) return;
  float hin[32];
  #pragma unroll
  for (int j = 0; j < 32; j++) hin[j] = h[(size_t)n*32 + j];
  float m[16];
  #pragma unroll
  for (int o = 0; o < 16; o++){
    float a = sb3[o];
    #pragma unroll
    for (int j = 0; j < 32; j++) a += hin[j]*sW3[j*16 + o];
    m[o] = fmaxf(a, 0.f);
  }
  float o0 = sb4[0], o1 = sb4[1];
  #pragma unroll
  for (int j = 0; j < 16; j++){ o0 += m[j]*sW4[j*2]; o1 += m[j]*sW4[j*2+1]; }
  out[(size_t)n*2]     = o0;
  out[(size_t)n*2 + 1] = o1;
}

extern "C" void kernel_launch(void* const* d_in, const int* in_sizes, int n_in,
                              void* d_out, int out_size, void* d_ws, size_t ws_size,
                              hipStream_t stream){
  const float* x     = (const float*)d_in[0];
  const int*   ei    = (const int*)  d_in[1];
  const float* fc1_w = (const float*)d_in[2];
  const float* fc1_b = (const float*)d_in[3];
  const float* fc2_w = (const float*)d_in[4];
  const float* fc2_b = (const float*)d_in[5];
  const float* a_iw[4] = {(const float*)d_in[6],  (const float*)d_in[9],  (const float*)d_in[12], (const float*)d_in[15]};
  const float* a_rw[4] = {(const float*)d_in[7],  (const float*)d_in[10], (const float*)d_in[13], (const float*)d_in[16]};
  const float* a_b [4] = {(const float*)d_in[8],  (const float*)d_in[11], (const float*)d_in[14], (const float*)d_in[17]};
  const float* fc3_w = (const float*)d_in[18];
  const float* fc3_b = (const float*)d_in[19];
  const float* fc4_w = (const float*)d_in[20];
  const float* fc4_b = (const float*)d_in[21];

  const int N = in_sizes[0] / 4;
  const int E = in_sizes[1] / 2;
  const int* row = ei;
  const int* col = ei + E;

  char* p = (char*)d_ws;
  auto alloc = [&](size_t bytes)->void*{
    void* q = (void*)p;
    p += (bytes + 255) & ~size_t(255);
    return q;
  };
  float*    dis    = (float*)   alloc((size_t)N*4);
  int*      cnt    = (int*)     alloc((size_t)N*4);
  int*      off    = (int*)     alloc((size_t)N*4);
  int*      cursor = (int*)     alloc((size_t)N*4);
  const int nb     = (N + 1023) / 1024;
  int*      bsums  = (int*)     alloc((size_t)nb*4);
  int*      esrc   = (int*)     alloc((size_t)E*4);
  float*    h1     = (float*)   alloc((size_t)N*128*4);
  ushort_t* h1b    = (ushort_t*)alloc((size_t)N*128*2);
  float*    aggH1  = (float*)   alloc((size_t)N*128*4);
  float*    hmid   = (float*)   alloc((size_t)N*32*4);
  float*    h2     = (float*)   alloc((size_t)N*32*4);
  float*    h3     = (float*)   alloc((size_t)N*32*4);
  float*    aggS   = (float*)   alloc((size_t)N*32*4);
  float*    WpFC2  = (float*)   alloc((size_t)32*128*4);
  float*    Wp1    = (float*)   alloc((size_t)256*128*4);
  float*    Wp2    = (float*)   alloc((size_t)64*128*4);
  float*    Wp3    = (float*)   alloc((size_t)64*128*4);
  float*    Wp4    = (float*)   alloc((size_t)64*128*4);
  float*    WpA[4] = {Wp1, Wp2, Wp3, Wp4};

  hipMemsetAsync(cnt, 0, (size_t)N*4, stream);
  k_deg  <<<(E+TPB-1)/TPB, TPB, 0, stream>>>(col, E, cnt);
  k_scan1<<<nb, TPB, 0, stream>>>(cnt, N, off, bsums, dis);
  k_scan2<<<1, 1, 0, stream>>>(bsums, nb);
  k_scan3<<<(N+TPB-1)/TPB, TPB, 0, stream>>>(off, cursor, bsums, N);
  k_fill <<<(E+TPB-1)/TPB, TPB, 0, stream>>>(row, col, E, cursor, esrc);

  // weight prep (tiny)
  k_wprep_fc  <<<(32*128+TPB-1)/TPB,  TPB, 0, stream>>>(fc2_w, 32, WpFC2);
  k_wprep_arma<<<(2*128*128+TPB-1)/TPB, TPB, 0, stream>>>(a_iw[0], a_rw[0], 128, Wp1);
  for (int L = 1; L < 4; L++)
    k_wprep_arma<<<(2*32*128+TPB-1)/TPB, TPB, 0, stream>>>(a_iw[L], a_rw[L], 32, WpA[L]);

  const int gg = (N + 255) / 256;
  k_fc1<<<((size_t)N*32+TPB-1)/TPB, TPB, 0, stream>>>(x, fc1_w, fc1_b, hmid, N);
  k_gemm<32,1,1,2><<<gg, TPB, 0, stream>>>(hmid, hmid, WpFC2, fc2_b, h1, h1b, N);

  // ARMA 1 (fin=128): bf16 gather, unified GEMM -> h2
  k_gather16<<<(N+7)/8, TPB, 0, stream>>>(h1b, off, cnt, esrc, dis, aggH1, N);
  k_gemm<128,8,4,0><<<gg, TPB, 0, stream>>>(aggH1, h1, Wp1, a_b[0], h2, h1b, N);

  // ARMA 2..4 (fin=32): ping-pong h2 <-> h3
  const float* hin = h2; float* hout = h3;
  for (int L = 1; L < 4; L++){
    k_gather32<<<(N+31)/32, TPB, 0, stream>>>(hin, off, cnt, esrc, dis, aggS, N);
    k_gemm<32,2,1,0><<<gg, TPB, 0, stream>>>(aggS, hin, WpA[L], a_b[L], hout, h1b, N);
    const float* tmp = hin; hin = hout; hout = (float*)tmp;
  }

  // after 3 swaps: final ARMA output in h3
  k_head<<<(N+TPB-1)/TPB, TPB, 0, stream>>>(h3, fc3_w, fc3_b, fc4_w, fc4_b, (float*)d_out, N);
}

// Round 10
// 593.757 us; speedup vs baseline: 2.5883x; 1.1805x over previous
//
#include <hip/hip_runtime.h>
#include <cstdint>

#define TPB 256
#define NBLK_A 512      // blocks in binning phase
#define BKT_SH 8        // 256 nodes per bucket; NB = ceil(N/256) (<=1024 assumed)

typedef unsigned short ushort_t;

__device__ __forceinline__ ushort_t bf16rne(float f){
  unsigned u = __float_as_uint(f);
  u += 0x7FFFu + ((u >> 16) & 1u);
  return (ushort_t)(u >> 16);
}
__device__ __forceinline__ float bf16f(ushort_t u){
  return __uint_as_float(((unsigned)u) << 16);
}

// ---------- A1: per-block LDS histogram of bucket ids ----------
__global__ void k_hist(const int* __restrict__ col, int E, int NB, int chunk,
                       int* __restrict__ hist /*[NB][NBLK_A]*/){
  __shared__ int lh[1024];
  int b = blockIdx.x, t = threadIdx.x;
  for (int i = t; i < NB; i += TPB) lh[i] = 0;
  __syncthreads();
  int s = b*chunk, e = min(E, s + chunk);
  for (int i = s + t; i < e; i += TPB)
    atomicAdd(&lh[col[i] >> BKT_SH], 1);
  __syncthreads();
  for (int j = t; j < NB; j += TPB) hist[(size_t)j*NBLK_A + b] = lh[j];
}

// ---------- A2a: per-bucket exclusive scan over blocks ----------
__global__ void k_bs1(int* __restrict__ hist, int* __restrict__ btot){
  __shared__ int lh[NBLK_A];
  int j = blockIdx.x, t = threadIdx.x;
  for (int b = t; b < NBLK_A; b += TPB) lh[b] = hist[(size_t)j*NBLK_A + b];
  __syncthreads();
  if (t == 0){
    int run = 0;
    for (int b = 0; b < NBLK_A; b++){ int v = lh[b]; lh[b] = run; run += v; }
    btot[j] = run;
  }
  __syncthreads();
  for (int b = t; b < NBLK_A; b += TPB) hist[(size_t)j*NBLK_A + b] = lh[b];
}

// ---------- A2b: exclusive scan over buckets ----------
__global__ void k_bs2(const int* __restrict__ btot, int NB, int* __restrict__ bbase){
  if (blockIdx.x == 0 && threadIdx.x == 0){
    int a = 0;
    for (int j = 0; j < NB; j++){ bbase[j] = a; a += btot[j]; }
    bbase[NB] = a;
  }
}

// ---------- A3: bin edges into bucket-major order (LDS cursors, no global atomics) ----------
__global__ void k_bin(const int* __restrict__ row, const int* __restrict__ col, int E,
                      int NB, int chunk, const int* __restrict__ hist,
                      const int* __restrict__ bbase, int2* __restrict__ binned){
  __shared__ int lcur[1024];
  int b = blockIdx.x, t = threadIdx.x;
  for (int i = t; i < NB; i += TPB) lcur[i] = 0;
  __syncthreads();
  int s = b*chunk, e = min(E, s + chunk);
  for (int i = s + t; i < e; i += TPB){
    int r = row[i], c = col[i];
    int j = c >> BKT_SH;
    int rk = atomicAdd(&lcur[j], 1);
    int pos = bbase[j] + hist[(size_t)j*NBLK_A + b] + rk;
    binned[pos] = make_int2(r, c);
  }
}

// ---------- B1: per-bucket degree count (LDS), replaces k_deg ----------
__global__ void k_cnt(const int2* __restrict__ binned, const int* __restrict__ bbase,
                      int N, int* __restrict__ cnt){
  __shared__ int lc[256];
  int j = blockIdx.x, t = threadIdx.x;
  int base = j << BKT_SH;
  lc[t] = 0;
  __syncthreads();
  int s = bbase[j], e = bbase[j+1];
  for (int i = s + t; i < e; i += TPB)
    atomicAdd(&lc[binned[i].y - base], 1);
  __syncthreads();
  if (base + t < N) cnt[base + t] = lc[t];
}

// ---------- exclusive scan of cnt -> off, fused deg^-1/2 ----------
__global__ void k_scan1(const int* __restrict__ cnt, int N, int* __restrict__ out,
                        int* __restrict__ bsums, float* __restrict__ dis){
  __shared__ int wsum[4];
  int t = threadIdx.x;
  int base = blockIdx.x*1024 + t*4;
  int v0 = (base+0 < N) ? cnt[base+0] : 0;
  int v1 = (base+1 < N) ? cnt[base+1] : 0;
  int v2 = (base+2 < N) ? cnt[base+2] : 0;
  int v3 = (base+3 < N) ? cnt[base+3] : 0;
  if (base+0 < N) dis[base+0] = (v0 > 0) ? rsqrtf((float)v0) : 0.f;
  if (base+1 < N) dis[base+1] = (v1 > 0) ? rsqrtf((float)v1) : 0.f;
  if (base+2 < N) dis[base+2] = (v2 > 0) ? rsqrtf((float)v2) : 0.f;
  if (base+3 < N) dis[base+3] = (v3 > 0) ? rsqrtf((float)v3) : 0.f;
  int tot = v0+v1+v2+v3;
  int lane = t & 63, wid = t >> 6;
  int x = tot;
  for (int d = 1; d < 64; d <<= 1){ int y = __shfl_up(x, d); if (lane >= d) x += y; }
  if (lane == 63) wsum[wid] = x;
  __syncthreads();
  if (t == 0){ int a = 0; for (int w = 0; w < 4; w++){ int s = wsum[w]; wsum[w] = a; a += s; } bsums[blockIdx.x] = a; }
  __syncthreads();
  int run = x - tot + wsum[wid];
  if (base+0 < N) out[base+0] = run; run += v0;
  if (base+1 < N) out[base+1] = run; run += v1;
  if (base+2 < N) out[base+2] = run; run += v2;
  if (base+3 < N) out[base+3] = run;
}

__global__ void k_scan2(int* __restrict__ bsums, int nb){
  if (blockIdx.x == 0 && threadIdx.x == 0){
    int a = 0;
    for (int i = 0; i < nb; i++){ int s = bsums[i]; bsums[i] = a; a += s; }
  }
}

__global__ void k_scan3(int* __restrict__ off, const int* __restrict__ bsums, int N){
  int i = blockIdx.x*blockDim.x + threadIdx.x;
  if (i < N) off[i] += bsums[i >> 10];
}

// ---------- B2: per-bucket CSR scatter (LDS cursors, L2-local window) ----------
__global__ void k_scatter(const int2* __restrict__ binned, const int* __restrict__ bbase,
                          const int* __restrict__ off, int N, int* __restrict__ esrc){
  __shared__ int lcur[256];
  int j = blockIdx.x, t = threadIdx.x;
  int base = j << BKT_SH;
  lcur[t] = (base + t < N) ? off[base + t] : 0;
  __syncthreads();
  int s = bbase[j], e = bbase[j+1];
  for (int i = s + t; i < e; i += TPB){
    int2 ed = binned[i];
    int p = atomicAdd(&lcur[ed.y - base], 1);
    esrc[p] = ed.x;
  }
}

// ---------- fc1: x(N,4) -> relu(x@W1+b1) (N,32) ----------
__global__ void k_fc1(const float* __restrict__ x, const float* __restrict__ W1,
                      const float* __restrict__ b1, float* __restrict__ hmid, int N){
  __shared__ float sW[128], sb[32];
  int t = threadIdx.x;
  if (t < 128) sW[t] = W1[t];
  if (t < 32)  sb[t] = b1[t];
  __syncthreads();
  int i = blockIdx.x*TPB + t;
  if (i >= N*32) return;
  int n = i >> 5, o = i & 31;
  float4 xv = *(const float4*)&x[(size_t)n*4];
  float a = sb[o] + xv.x*sW[o] + xv.y*sW[32+o] + xv.z*sW[64+o] + xv.w*sW[96+o];
  hmid[i] = fmaxf(a, 0.f);
}

// ---------- weight prep: permuted columns pos(o) ----------
// pos(o): k=o>>5, og=(o&31)>>1, j=o&1 -> (k>>1)*64 + og*4 + (k&1)*2 + j   (m = 2k+j)
__global__ void k_wprep_arma(const float* __restrict__ iw, const float* __restrict__ rw,
                             int F, float* __restrict__ dst){
  int idx = blockIdx.x*TPB + threadIdx.x;
  if (idx >= 2*F*128) return;
  int f2 = idx >> 7, o = idx & 127;
  int k = o >> 5, og = (o & 31) >> 1, j = o & 1;
  int pos = (k >> 1)*64 + og*4 + (k & 1)*2 + j;
  float v = (f2 < F) ? iw[(k*F + f2)*32 + (o & 31)]
                     : rw[(k*F + (f2 - F))*32 + (o & 31)];
  dst[f2*128 + pos] = v;
}

__global__ void k_wprep_fc(const float* __restrict__ W, int F, float* __restrict__ dst){
  int idx = blockIdx.x*TPB + threadIdx.x;
  if (idx >= F*128) return;
  int f = idx >> 7, o = idx & 127;
  int k = o >> 5, og = (o & 31) >> 1, j = o & 1;
  int pos = (k >> 1)*64 + og*4 + (k & 1)*2 + j;
  dst[f*128 + pos] = W[f*128 + o];
}

// ---------- L1 gather (bf16 table, 128 cols): aggH[n,:] = dis[n] * sum_e dis[src]*hb[src,:] ----------
__global__ void k_gather16(const ushort_t* __restrict__ hb, const int* __restrict__ off,
                           const int* __restrict__ cnt, const int* __restrict__ esrc,
                           const float* __restrict__ dis, float* __restrict__ aggH, int N){
  int t = threadIdx.x;
  int g = t >> 5, l = t & 31;            // 32 lanes/node, 4 bf16 cols each
  int n = blockIdx.x*8 + g;
  if (n >= N) return;
  int s = off[n], c = cnt[n];
  float4 accA = make_float4(0.f,0.f,0.f,0.f);
  float4 accB = make_float4(0.f,0.f,0.f,0.f);
  int i = 0;
  for (; i + 3 < c; i += 4){
    int s0 = esrc[s+i], s1 = esrc[s+i+1], s2 = esrc[s+i+2], s3 = esrc[s+i+3];
    float w0 = dis[s0], w1 = dis[s1], w2 = dis[s2], w3 = dis[s3];
    ushort4 u0 = *(const ushort4*)&hb[(size_t)s0*128 + 4*l];
    ushort4 u1 = *(const ushort4*)&hb[(size_t)s1*128 + 4*l];
    ushort4 u2 = *(const ushort4*)&hb[(size_t)s2*128 + 4*l];
    ushort4 u3 = *(const ushort4*)&hb[(size_t)s3*128 + 4*l];
    accA.x += w0*bf16f(u0.x) + w1*bf16f(u1.x);
    accA.y += w0*bf16f(u0.y) + w1*bf16f(u1.y);
    accA.z += w0*bf16f(u0.z) + w1*bf16f(u1.z);
    accA.w += w0*bf16f(u0.w) + w1*bf16f(u1.w);
    accB.x += w2*bf16f(u2.x) + w3*bf16f(u3.x);
    accB.y += w2*bf16f(u2.y) + w3*bf16f(u3.y);
    accB.z += w2*bf16f(u2.z) + w3*bf16f(u3.z);
    accB.w += w2*bf16f(u2.w) + w3*bf16f(u3.w);
  }
  for (; i < c; i++){
    int s0 = esrc[s+i];
    float w0 = dis[s0];
    ushort4 u0 = *(const ushort4*)&hb[(size_t)s0*128 + 4*l];
    accA.x += w0*bf16f(u0.x); accA.y += w0*bf16f(u0.y);
    accA.z += w0*bf16f(u0.z); accA.w += w0*bf16f(u0.w);
  }
  float wn = dis[n];
  float4 r;
  r.x = wn*(accA.x + accB.x); r.y = wn*(accA.y + accB.y);
  r.z = wn*(accA.z + accB.z); r.w = wn*(accA.w + accB.w);
  *(float4*)&aggH[(size_t)n*128 + 4*l] = r;
}

// ---------- small gather (fp32 table, 32 cols) ----------
__global__ void k_gather32(const float* __restrict__ h, const int* __restrict__ off,
                           const int* __restrict__ cnt, const int* __restrict__ esrc,
                           const float* __restrict__ dis, float* __restrict__ agg, int N){
  int t = threadIdx.x;
  int g = t >> 3, l = t & 7;             // 8 lanes/node, float4 each
  int n = blockIdx.x*32 + g;
  if (n >= N) return;
  int s = off[n], c = cnt[n];
  float4 accA = make_float4(0.f,0.f,0.f,0.f);
  float4 accB = make_float4(0.f,0.f,0.f,0.f);
  int i = 0;
  for (; i + 3 < c; i += 4){
    int s0 = esrc[s+i], s1 = esrc[s+i+1], s2 = esrc[s+i+2], s3 = esrc[s+i+3];
    float w0 = dis[s0], w1 = dis[s1], w2 = dis[s2], w3 = dis[s3];
    float4 v0 = *(const float4*)&h[(size_t)s0*32 + 4*l];
    float4 v1 = *(const float4*)&h[(size_t)s1*32 + 4*l];
    float4 v2 = *(const float4*)&h[(size_t)s2*32 + 4*l];
    float4 v3 = *(const float4*)&h[(size_t)s3*32 + 4*l];
    accA.x += w0*v0.x + w1*v1.x;  accA.y += w0*v0.y + w1*v1.y;
    accA.z += w0*v0.z + w1*v1.z;  accA.w += w0*v0.w + w1*v1.w;
    accB.x += w2*v2.x + w3*v3.x;  accB.y += w2*v2.y + w3*v3.y;
    accB.z += w2*v2.z + w3*v3.z;  accB.w += w2*v2.w + w3*v3.w;
  }
  for (; i < c; i++){
    int s0 = esrc[s+i];
    float w0 = dis[s0];
    float4 v0 = *(const float4*)&h[(size_t)s0*32 + 4*l];
    accA.x += w0*v0.x; accA.y += w0*v0.y; accA.z += w0*v0.z; accA.w += w0*v0.w;
  }
  float wn = dis[n];
  float4 r;
  r.x = wn*(accA.x + accB.x); r.y = wn*(accA.y + accB.y);
  r.z = wn*(accA.z + accB.z); r.w = wn*(accA.w + accB.w);
  *(float4*)&agg[(size_t)n*32 + 4*l] = r;
}

// ---------- unified GEMM: out = [srcA|srcB](N,32*T) @ Wp(32*T,128) ----------
// MODE 0: ARMA epilogue: out(N,32) = 0.25*sum_k relu(col + bias)
// MODE 1: plain: out(N,128) = relu(col + bias)
// MODE 2: plain + bf16 copy to out2
template<int F, int T, int TA, int MODE>
__global__ __launch_bounds__(256, 2) void k_gemm(
    const float* __restrict__ srcA, const float* __restrict__ srcB,
    const float* __restrict__ Wp, const float* __restrict__ bias,
    float* __restrict__ out, ushort_t* __restrict__ out2, int N){
  __shared__ float sG[32*260];
  __shared__ float sW[32*132];
  int t = threadIdx.x;
  int ng = t >> 4, og = t & 15;
  int n0 = blockIdx.x*256;

  float acc[16][8];
  #pragma unroll
  for (int i = 0; i < 16; i++)
    #pragma unroll
    for (int m = 0; m < 8; m++) acc[i][m] = 0.f;

  for (int tt = 0; tt < T; ++tt){
    const float* src = (tt < TA) ? srcA : srcB;
    int fb = (tt < TA) ? tt*32 : (tt - TA)*32;
    __syncthreads();
    #pragma unroll
    for (int j = 0; j < 4; j++){
      int q = t + j*256;
      int fr = q >> 5, c4 = (q & 31)*4;
      *(float4*)&sW[fr*132 + c4] = *(const float4*)&Wp[(tt*32 + fr)*128 + c4];
    }
    #pragma unroll
    for (int j = 0; j < 8; j++){
      int q = t + j*256;
      int n = q & 255, f4 = (q >> 8)*4;
      int node = n0 + n;
      float4 v = make_float4(0.f,0.f,0.f,0.f);
      if (node < N) v = *(const float4*)&src[(size_t)node*F + fb + f4];
      sG[(f4+0)*260 + n] = v.x;
      sG[(f4+1)*260 + n] = v.y;
      sG[(f4+2)*260 + n] = v.z;
      sG[(f4+3)*260 + n] = v.w;
    }
    __syncthreads();
    #pragma unroll 4
    for (int f = 0; f < 32; f++){
      float4 a0 = *(float4*)&sG[f*260 + 16*ng];
      float4 a1 = *(float4*)&sG[f*260 + 16*ng + 4];
      float4 a2 = *(float4*)&sG[f*260 + 16*ng + 8];
      float4 a3 = *(float4*)&sG[f*260 + 16*ng + 12];
      float4 w0 = *(float4*)&sW[f*132 + 4*og];
      float4 w1 = *(float4*)&sW[f*132 + 64 + 4*og];
      float av[16] = {a0.x,a0.y,a0.z,a0.w, a1.x,a1.y,a1.z,a1.w,
                      a2.x,a2.y,a2.z,a2.w, a3.x,a3.y,a3.z,a3.w};
      float wv[8]  = {w0.x,w0.y,w0.z,w0.w, w1.x,w1.y,w1.z,w1.w};
      #pragma unroll
      for (int i = 0; i < 16; i++)
        #pragma unroll
        for (int m = 0; m < 8; m++) acc[i][m] += av[i]*wv[m];
    }
  }

  float bb[8];
  #pragma unroll
  for (int m = 0; m < 8; m++) bb[m] = bias[(m >> 1)*32 + 2*og + (m & 1)];

  #pragma unroll
  for (int i = 0; i < 16; i++){
    int n = n0 + 16*ng + i;
    if (n >= N) continue;
    if (MODE == 0){
      float s0 = 0.f, s1 = 0.f;
      #pragma unroll
      for (int k = 0; k < 4; k++){
        s0 += fmaxf(acc[i][2*k]   + bb[2*k],   0.f);
        s1 += fmaxf(acc[i][2*k+1] + bb[2*k+1], 0.f);
      }
      float2 v; v.x = 0.25f*s0; v.y = 0.25f*s1;
      *(float2*)&out[(size_t)n*32 + 2*og] = v;
    } else {
      #pragma unroll
      for (int k = 0; k < 4; k++){
        float2 v;
        v.x = fmaxf(acc[i][2*k]   + bb[2*k],   0.f);
        v.y = fmaxf(acc[i][2*k+1] + bb[2*k+1], 0.f);
        *(float2*)&out[(size_t)n*128 + k*32 + 2*og] = v;
        if (MODE == 2){
          ushort2 u; u.x = bf16rne(v.x); u.y = bf16rne(v.y);
          *(ushort2*)&out2[(size_t)n*128 + k*32 + 2*og] = u;
        }
      }
    }
  }
}

// ---------- head: relu(h@W3+b3)@W4+b4 ----------
__global__ void k_head(const float* __restrict__ h,
                       const float* __restrict__ W3, const float* __restrict__ b3,
                       const float* __restrict__ W4, const float* __restrict__ b4,
                       float* __restrict__ out, int N){
  __shared__ float sW3[32*16], sb3[16], sW4[16*2], sb4[2];
  int t = threadIdx.x;
  for (int i = t; i < 512; i += TPB) sW3[i] = W3[i];
  if (t < 16) sb3[t] = b3[t];
  if (t < 32) sW4[t] = W4[t];
  if (t < 2)  sb4[t] = b4[t];
  __syncthreads();
  int n = blockIdx.x*TPB + t;
  if (n >= N) return;
  float hin[32];
  #pragma unroll
  for (int j = 0; j < 32; j++) hin[j] = h[(size_t)n*32 + j];
  float m[16];
  #pragma unroll
  for (int o = 0; o < 16; o++){
    float a = sb3[o];
    #pragma unroll
    for (int j = 0; j < 32; j++) a += hin[j]*sW3[j*16 + o];
    m[o] = fmaxf(a, 0.f);
  }
  float o0 = sb4[0], o1 = sb4[1];
  #pragma unroll
  for (int j = 0; j < 16; j++){ o0 += m[j]*sW4[j*2]; o1 += m[j]*sW4[j*2+1]; }
  out[(size_t)n*2]     = o0;
  out[(size_t)n*2 + 1] = o1;
}

extern "C" void kernel_launch(void* const* d_in, const int* in_sizes, int n_in,
                              void* d_out, int out_size, void* d_ws, size_t ws_size,
                              hipStream_t stream){
  const float* x     = (const float*)d_in[0];
  const int*   ei    = (const int*)  d_in[1];
  const float* fc1_w = (const float*)d_in[2];
  const float* fc1_b = (const float*)d_in[3];
  const float* fc2_w = (const float*)d_in[4];
  const float* fc2_b = (const float*)d_in[5];
  const float* a_iw[4] = {(const float*)d_in[6],  (const float*)d_in[9],  (const float*)d_in[12], (const float*)d_in[15]};
  const float* a_rw[4] = {(const float*)d_in[7],  (const float*)d_in[10], (const float*)d_in[13], (const float*)d_in[16]};
  const float* a_b [4] = {(const float*)d_in[8],  (const float*)d_in[11], (const float*)d_in[14], (const float*)d_in[17]};
  const float* fc3_w = (const float*)d_in[18];
  const float* fc3_b = (const float*)d_in[19];
  const float* fc4_w = (const float*)d_in[20];
  const float* fc4_b = (const float*)d_in[21];

  const int N = in_sizes[0] / 4;
  const int E = in_sizes[1] / 2;
  const int* row = ei;
  const int* col = ei + E;
  const int NB = (N + 255) >> BKT_SH;          // buckets of 256 nodes (<=1024)
  const int chunk = (E + NBLK_A - 1) / NBLK_A;

  char* p = (char*)d_ws;
  auto alloc = [&](size_t bytes)->void*{
    void* q = (void*)p;
    p += (bytes + 255) & ~size_t(255);
    return q;
  };
  float*    dis    = (float*)   alloc((size_t)N*4);
  int*      cnt    = (int*)     alloc((size_t)N*4);
  int*      off    = (int*)     alloc((size_t)N*4);
  const int nb     = (N + 1023) / 1024;
  int*      bsums  = (int*)     alloc((size_t)nb*4);
  int*      esrc   = (int*)     alloc((size_t)E*4);
  int2*     binned = (int2*)    alloc((size_t)E*8);
  int*      hist   = (int*)     alloc((size_t)NB*NBLK_A*4);
  int*      btot   = (int*)     alloc((size_t)NB*4);
  int*      bbase  = (int*)     alloc((size_t)(NB+1)*4);
  float*    h1     = (float*)   alloc((size_t)N*128*4);
  ushort_t* h1b    = (ushort_t*)alloc((size_t)N*128*2);
  float*    aggH1  = (float*)   alloc((size_t)N*128*4);
  float*    hmid   = (float*)   alloc((size_t)N*32*4);
  float*    h2     = (float*)   alloc((size_t)N*32*4);
  float*    h3     = (float*)   alloc((size_t)N*32*4);
  float*    aggS   = (float*)   alloc((size_t)N*32*4);
  float*    WpFC2  = (float*)   alloc((size_t)32*128*4);
  float*    Wp1    = (float*)   alloc((size_t)256*128*4);
  float*    Wp2    = (float*)   alloc((size_t)64*128*4);
  float*    Wp3    = (float*)   alloc((size_t)64*128*4);
  float*    Wp4    = (float*)   alloc((size_t)64*128*4);
  float*    WpA[4] = {Wp1, Wp2, Wp3, Wp4};

  // ---- atomic-free bucketed CSR build ----
  k_hist   <<<NBLK_A, TPB, 0, stream>>>(col, E, NB, chunk, hist);
  k_bs1    <<<NB, TPB, 0, stream>>>(hist, btot);
  k_bs2    <<<1, 1, 0, stream>>>(btot, NB, bbase);
  k_bin    <<<NBLK_A, TPB, 0, stream>>>(row, col, E, NB, chunk, hist, bbase, binned);
  k_cnt    <<<NB, TPB, 0, stream>>>(binned, bbase, N, cnt);
  k_scan1  <<<nb, TPB, 0, stream>>>(cnt, N, off, bsums, dis);
  k_scan2  <<<1, 1, 0, stream>>>(bsums, nb);
  k_scan3  <<<(N+TPB-1)/TPB, TPB, 0, stream>>>(off, bsums, N);
  k_scatter<<<NB, TPB, 0, stream>>>(binned, bbase, off, N, esrc);

  // weight prep (tiny)
  k_wprep_fc  <<<(32*128+TPB-1)/TPB,  TPB, 0, stream>>>(fc2_w, 32, WpFC2);
  k_wprep_arma<<<(2*128*128+TPB-1)/TPB, TPB, 0, stream>>>(a_iw[0], a_rw[0], 128, Wp1);
  for (int L = 1; L < 4; L++)
    k_wprep_arma<<<(2*32*128+TPB-1)/TPB, TPB, 0, stream>>>(a_iw[L], a_rw[L], 32, WpA[L]);

  const int gg = (N + 255) / 256;
  k_fc1<<<((size_t)N*32+TPB-1)/TPB, TPB, 0, stream>>>(x, fc1_w, fc1_b, hmid, N);
  k_gemm<32,1,1,2><<<gg, TPB, 0, stream>>>(hmid, hmid, WpFC2, fc2_b, h1, h1b, N);

  // ARMA 1 (fin=128): bf16 gather, unified GEMM -> h2
  k_gather16<<<(N+7)/8, TPB, 0, stream>>>(h1b, off, cnt, esrc, dis, aggH1, N);
  k_gemm<128,8,4,0><<<gg, TPB, 0, stream>>>(aggH1, h1, Wp1, a_b[0], h2, h1b, N);

  // ARMA 2..4 (fin=32): ping-pong h2 <-> h3
  const float* hin = h2; float* hout = h3;
  for (int L = 1; L < 4; L++){
    k_gather32<<<(N+31)/32, TPB, 0, stream>>>(hin, off, cnt, esrc, dis, aggS, N);
    k_gemm<32,2,1,0><<<gg, TPB, 0, stream>>>(aggS, hin, WpA[L], a_b[L], hout, h1b, N);
    const float* tmp = hin; hin = hout; hout = (float*)tmp;
  }

  // after 3 swaps: final ARMA output in h3
  k_head<<<(N+TPB-1)/TPB, TPB, 0, stream>>>(h3, fc3_w, fc3_b, fc4_w, fc4_b, (float*)d_out, N);
}

// Round 11
// 591.816 us; speedup vs baseline: 2.5968x; 1.0033x over previous
//
#include <hip/hip_runtime.h>
#include <cstdint>

#define TPB 256
#define NBLK_A 512      // blocks in binning phase
#define BKT_SH 8        // 256 nodes per bucket; NB = ceil(N/256) (<=1024 assumed)

typedef unsigned short ushort_t;

__device__ __forceinline__ ushort_t bf16rne(float f){
  unsigned u = __float_as_uint(f);
  u += 0x7FFFu + ((u >> 16) & 1u);
  return (ushort_t)(u >> 16);
}
__device__ __forceinline__ float bf16lo(unsigned u){ return __uint_as_float(u << 16); }
__device__ __forceinline__ float bf16hi(unsigned u){ return __uint_as_float(u & 0xFFFF0000u); }

// ---------- A1: per-block LDS histogram of bucket ids ----------
__global__ void k_hist(const int* __restrict__ col, int E, int NB, int chunk,
                       int* __restrict__ hist /*[NB][NBLK_A]*/){
  __shared__ int lh[1024];
  int b = blockIdx.x, t = threadIdx.x;
  for (int i = t; i < NB; i += TPB) lh[i] = 0;
  __syncthreads();
  int s = b*chunk, e = min(E, s + chunk);
  for (int i = s + t; i < e; i += TPB)
    atomicAdd(&lh[col[i] >> BKT_SH], 1);
  __syncthreads();
  for (int j = t; j < NB; j += TPB) hist[(size_t)j*NBLK_A + b] = lh[j];
}

// ---------- A2a: per-bucket exclusive scan over blocks ----------
__global__ void k_bs1(int* __restrict__ hist, int* __restrict__ btot){
  __shared__ int lh[NBLK_A];
  int j = blockIdx.x, t = threadIdx.x;
  for (int b = t; b < NBLK_A; b += TPB) lh[b] = hist[(size_t)j*NBLK_A + b];
  __syncthreads();
  if (t == 0){
    int run = 0;
    for (int b = 0; b < NBLK_A; b++){ int v = lh[b]; lh[b] = run; run += v; }
    btot[j] = run;
  }
  __syncthreads();
  for (int b = t; b < NBLK_A; b += TPB) hist[(size_t)j*NBLK_A + b] = lh[b];
}

// ---------- A2b: exclusive scan over buckets ----------
__global__ void k_bs2(const int* __restrict__ btot, int NB, int* __restrict__ bbase){
  if (blockIdx.x == 0 && threadIdx.x == 0){
    int a = 0;
    for (int j = 0; j < NB; j++){ bbase[j] = a; a += btot[j]; }
    bbase[NB] = a;
  }
}

// ---------- A3: bin edges into bucket-major order (LDS cursors) ----------
__global__ void k_bin(const int* __restrict__ row, const int* __restrict__ col, int E,
                      int NB, int chunk, const int* __restrict__ hist,
                      const int* __restrict__ bbase, int2* __restrict__ binned){
  __shared__ int lcur[1024];
  int b = blockIdx.x, t = threadIdx.x;
  for (int i = t; i < NB; i += TPB) lcur[i] = 0;
  __syncthreads();
  int s = b*chunk, e = min(E, s + chunk);
  for (int i = s + t; i < e; i += TPB){
    int r = row[i], c = col[i];
    int j = c >> BKT_SH;
    int rk = atomicAdd(&lcur[j], 1);
    int pos = bbase[j] + hist[(size_t)j*NBLK_A + b] + rk;
    binned[pos] = make_int2(r, c);
  }
}

// ---------- B1: per-bucket degree count (LDS) ----------
__global__ void k_cnt(const int2* __restrict__ binned, const int* __restrict__ bbase,
                      int N, int* __restrict__ cnt){
  __shared__ int lc[256];
  int j = blockIdx.x, t = threadIdx.x;
  int base = j << BKT_SH;
  lc[t] = 0;
  __syncthreads();
  int s = bbase[j], e = bbase[j+1];
  for (int i = s + t; i < e; i += TPB)
    atomicAdd(&lc[binned[i].y - base], 1);
  __syncthreads();
  if (base + t < N) cnt[base + t] = lc[t];
}

// ---------- exclusive scan of cnt -> off, fused deg^-1/2 ----------
__global__ void k_scan1(const int* __restrict__ cnt, int N, int* __restrict__ out,
                        int* __restrict__ bsums, float* __restrict__ dis){
  __shared__ int wsum[4];
  int t = threadIdx.x;
  int base = blockIdx.x*1024 + t*4;
  int v0 = (base+0 < N) ? cnt[base+0] : 0;
  int v1 = (base+1 < N) ? cnt[base+1] : 0;
  int v2 = (base+2 < N) ? cnt[base+2] : 0;
  int v3 = (base+3 < N) ? cnt[base+3] : 0;
  if (base+0 < N) dis[base+0] = (v0 > 0) ? rsqrtf((float)v0) : 0.f;
  if (base+1 < N) dis[base+1] = (v1 > 0) ? rsqrtf((float)v1) : 0.f;
  if (base+2 < N) dis[base+2] = (v2 > 0) ? rsqrtf((float)v2) : 0.f;
  if (base+3 < N) dis[base+3] = (v3 > 0) ? rsqrtf((float)v3) : 0.f;
  int tot = v0+v1+v2+v3;
  int lane = t & 63, wid = t >> 6;
  int x = tot;
  for (int d = 1; d < 64; d <<= 1){ int y = __shfl_up(x, d); if (lane >= d) x += y; }
  if (lane == 63) wsum[wid] = x;
  __syncthreads();
  if (t == 0){ int a = 0; for (int w = 0; w < 4; w++){ int s = wsum[w]; wsum[w] = a; a += s; } bsums[blockIdx.x] = a; }
  __syncthreads();
  int run = x - tot + wsum[wid];
  if (base+0 < N) out[base+0] = run; run += v0;
  if (base+1 < N) out[base+1] = run; run += v1;
  if (base+2 < N) out[base+2] = run; run += v2;
  if (base+3 < N) out[base+3] = run;
}

__global__ void k_scan2(int* __restrict__ bsums, int nb){
  if (blockIdx.x == 0 && threadIdx.x == 0){
    int a = 0;
    for (int i = 0; i < nb; i++){ int s = bsums[i]; bsums[i] = a; a += s; }
  }
}

__global__ void k_scan3(int* __restrict__ off, const int* __restrict__ bsums, int N){
  int i = blockIdx.x*blockDim.x + threadIdx.x;
  if (i < N) off[i] += bsums[i >> 10];
}

// ---------- B2: per-bucket CSR scatter (LDS cursors) ----------
__global__ void k_scatter(const int2* __restrict__ binned, const int* __restrict__ bbase,
                          const int* __restrict__ off, int N, int* __restrict__ esrc){
  __shared__ int lcur[256];
  int j = blockIdx.x, t = threadIdx.x;
  int base = j << BKT_SH;
  lcur[t] = (base + t < N) ? off[base + t] : 0;
  __syncthreads();
  int s = bbase[j], e = bbase[j+1];
  for (int i = s + t; i < e; i += TPB){
    int2 ed = binned[i];
    int p = atomicAdd(&lcur[ed.y - base], 1);
    esrc[p] = ed.x;
  }
}

// ---------- fc1: x(N,4) -> relu(x@W1+b1) (N,32) ----------
__global__ void k_fc1(const float* __restrict__ x, const float* __restrict__ W1,
                      const float* __restrict__ b1, float* __restrict__ hmid, int N){
  __shared__ float sW[128], sb[32];
  int t = threadIdx.x;
  if (t < 128) sW[t] = W1[t];
  if (t < 32)  sb[t] = b1[t];
  __syncthreads();
  int i = blockIdx.x*TPB + t;
  if (i >= N*32) return;
  int n = i >> 5, o = i & 31;
  float4 xv = *(const float4*)&x[(size_t)n*4];
  float a = sb[o] + xv.x*sW[o] + xv.y*sW[32+o] + xv.z*sW[64+o] + xv.w*sW[96+o];
  hmid[i] = fmaxf(a, 0.f);
}

// ---------- weight prep: permuted columns pos(o) ----------
// pos(o): k=o>>5, og=(o&31)>>1, j=o&1 -> (k>>1)*64 + og*4 + (k&1)*2 + j   (m = 2k+j)
__global__ void k_wprep_arma(const float* __restrict__ iw, const float* __restrict__ rw,
                             int F, float* __restrict__ dst){
  int idx = blockIdx.x*TPB + threadIdx.x;
  if (idx >= 2*F*128) return;
  int f2 = idx >> 7, o = idx & 127;
  int k = o >> 5, og = (o & 31) >> 1, j = o & 1;
  int pos = (k >> 1)*64 + og*4 + (k & 1)*2 + j;
  float v = (f2 < F) ? iw[(k*F + f2)*32 + (o & 31)]
                     : rw[(k*F + (f2 - F))*32 + (o & 31)];
  dst[f2*128 + pos] = v;
}

__global__ void k_wprep_fc(const float* __restrict__ W, int F, float* __restrict__ dst){
  int idx = blockIdx.x*TPB + threadIdx.x;
  if (idx >= F*128) return;
  int f = idx >> 7, o = idx & 127;
  int k = o >> 5, og = (o & 31) >> 1, j = o & 1;
  int pos = (k >> 1)*64 + og*4 + (k & 1)*2 + j;
  dst[f*128 + pos] = W[f*128 + o];
}

// ---------- bf16-table gather: agg[n,:] = dis[n] * sum_e dis[src]*hb[src,:] (COLS cols) ----------
template<int COLS>
__global__ void k_gatherb(const unsigned* __restrict__ hb /*as uint, 2 bf16 each*/,
                          const int* __restrict__ off, const int* __restrict__ cnt,
                          const int* __restrict__ esrc, const float* __restrict__ dis,
                          float* __restrict__ agg, int N){
  constexpr int LPN = COLS/8;            // lanes per node, uint4 = 8 bf16 each
  constexpr int NPB = TPB/LPN;
  constexpr int RW  = COLS/2;            // row width in uints
  int t = threadIdx.x;
  int g = t / LPN, l = t % LPN;
  int n = blockIdx.x*NPB + g;
  if (n >= N) return;
  int s = off[n], c = cnt[n];
  float acc[8];
  #pragma unroll
  for (int q = 0; q < 8; q++) acc[q] = 0.f;
  int i = 0;
  for (; i + 1 < c; i += 2){
    int s0 = esrc[s+i], s1 = esrc[s+i+1];
    float w0 = dis[s0], w1 = dis[s1];
    uint4 u0 = *(const uint4*)&hb[(size_t)s0*RW + 4*l];
    uint4 u1 = *(const uint4*)&hb[(size_t)s1*RW + 4*l];
    acc[0] += w0*bf16lo(u0.x) + w1*bf16lo(u1.x);
    acc[1] += w0*bf16hi(u0.x) + w1*bf16hi(u1.x);
    acc[2] += w0*bf16lo(u0.y) + w1*bf16lo(u1.y);
    acc[3] += w0*bf16hi(u0.y) + w1*bf16hi(u1.y);
    acc[4] += w0*bf16lo(u0.z) + w1*bf16lo(u1.z);
    acc[5] += w0*bf16hi(u0.z) + w1*bf16hi(u1.z);
    acc[6] += w0*bf16lo(u0.w) + w1*bf16lo(u1.w);
    acc[7] += w0*bf16hi(u0.w) + w1*bf16hi(u1.w);
  }
  if (i < c){
    int s0 = esrc[s+i];
    float w0 = dis[s0];
    uint4 u0 = *(const uint4*)&hb[(size_t)s0*RW + 4*l];
    acc[0] += w0*bf16lo(u0.x); acc[1] += w0*bf16hi(u0.x);
    acc[2] += w0*bf16lo(u0.y); acc[3] += w0*bf16hi(u0.y);
    acc[4] += w0*bf16lo(u0.z); acc[5] += w0*bf16hi(u0.z);
    acc[6] += w0*bf16lo(u0.w); acc[7] += w0*bf16hi(u0.w);
  }
  float wn = dis[n];
  float4 r0, r1;
  r0.x = wn*acc[0]; r0.y = wn*acc[1]; r0.z = wn*acc[2]; r0.w = wn*acc[3];
  r1.x = wn*acc[4]; r1.y = wn*acc[5]; r1.z = wn*acc[6]; r1.w = wn*acc[7];
  *(float4*)&agg[(size_t)n*COLS + 8*l]     = r0;
  *(float4*)&agg[(size_t)n*COLS + 8*l + 4] = r1;
}

// ---------- unified GEMM: out = [srcA|srcB](N,32*T) @ Wp(32*T,128) ----------
// 128 nodes x 128 outs per block; thread tile 8 nodes x 8 outs.
// MODE 0: ARMA epilogue: out(N,32) = 0.25*sum_k relu(col+bias), + bf16 copy to out2
// MODE 1: plain: out(N,128) = relu(col+bias)
// MODE 2: plain + bf16 copy to out2 (N,128)
template<int F, int T, int TA, int MODE>
__global__ __launch_bounds__(256, 4) void k_gemm(
    const float* __restrict__ srcA, const float* __restrict__ srcB,
    const float* __restrict__ Wp, const float* __restrict__ bias,
    float* __restrict__ out, ushort_t* __restrict__ out2, int N){
  __shared__ float sG[32*132];
  __shared__ float sW[32*132];
  int t = threadIdx.x;
  int ng = t >> 4, og = t & 15;
  int n0 = blockIdx.x*128;

  float acc[8][8];
  #pragma unroll
  for (int i = 0; i < 8; i++)
    #pragma unroll
    for (int m = 0; m < 8; m++) acc[i][m] = 0.f;

  for (int tt = 0; tt < T; ++tt){
    const float* src = (tt < TA) ? srcA : srcB;
    int fb = (tt < TA) ? tt*32 : (tt - TA)*32;
    __syncthreads();
    #pragma unroll
    for (int j = 0; j < 4; j++){
      int q = t + j*256;
      int fr = q >> 5, c4 = (q & 31)*4;
      *(float4*)&sW[fr*132 + c4] = *(const float4*)&Wp[(tt*32 + fr)*128 + c4];
    }
    #pragma unroll
    for (int j = 0; j < 4; j++){
      int q = t + j*256;
      int n = q & 127, f4 = (q >> 7)*4;
      int node = n0 + n;
      float4 v = make_float4(0.f,0.f,0.f,0.f);
      if (node < N) v = *(const float4*)&src[(size_t)node*F + fb + f4];
      sG[(f4+0)*132 + n] = v.x;
      sG[(f4+1)*132 + n] = v.y;
      sG[(f4+2)*132 + n] = v.z;
      sG[(f4+3)*132 + n] = v.w;
    }
    __syncthreads();
    #pragma unroll 4
    for (int f = 0; f < 32; f++){
      float4 a0 = *(float4*)&sG[f*132 + 8*ng];
      float4 a1 = *(float4*)&sG[f*132 + 8*ng + 4];
      float4 w0 = *(float4*)&sW[f*132 + 4*og];
      float4 w1 = *(float4*)&sW[f*132 + 64 + 4*og];
      float av[8] = {a0.x,a0.y,a0.z,a0.w, a1.x,a1.y,a1.z,a1.w};
      float wv[8] = {w0.x,w0.y,w0.z,w0.w, w1.x,w1.y,w1.z,w1.w};
      #pragma unroll
      for (int i = 0; i < 8; i++)
        #pragma unroll
        for (int m = 0; m < 8; m++) acc[i][m] += av[i]*wv[m];
    }
  }

  float bb[8];
  #pragma unroll
  for (int m = 0; m < 8; m++) bb[m] = bias[(m >> 1)*32 + 2*og + (m & 1)];

  #pragma unroll
  for (int i = 0; i < 8; i++){
    int n = n0 + 8*ng + i;
    if (n >= N) continue;
    if (MODE == 0){
      float s0 = 0.f, s1 = 0.f;
      #pragma unroll
      for (int k = 0; k < 4; k++){
        s0 += fmaxf(acc[i][2*k]   + bb[2*k],   0.f);
        s1 += fmaxf(acc[i][2*k+1] + bb[2*k+1], 0.f);
      }
      float2 v; v.x = 0.25f*s0; v.y = 0.25f*s1;
      *(float2*)&out[(size_t)n*32 + 2*og] = v;
      ushort2 u; u.x = bf16rne(v.x); u.y = bf16rne(v.y);
      *(ushort2*)&out2[(size_t)n*32 + 2*og] = u;
    } else {
      #pragma unroll
      for (int k = 0; k < 4; k++){
        float2 v;
        v.x = fmaxf(acc[i][2*k]   + bb[2*k],   0.f);
        v.y = fmaxf(acc[i][2*k+1] + bb[2*k+1], 0.f);
        *(float2*)&out[(size_t)n*128 + k*32 + 2*og] = v;
        if (MODE == 2){
          ushort2 u; u.x = bf16rne(v.x); u.y = bf16rne(v.y);
          *(ushort2*)&out2[(size_t)n*128 + k*32 + 2*og] = u;
        }
      }
    }
  }
}

// ---------- head: relu(h@W3+b3)@W4+b4 ----------
__global__ void k_head(const float* __restrict__ h,
                       const float* __restrict__ W3, const float* __restrict__ b3,
                       const float* __restrict__ W4, const float* __restrict__ b4,
                       float* __restrict__ out, int N){
  __shared__ float sW3[32*16], sb3[16], sW4[16*2], sb4[2];
  int t = threadIdx.x;
  for (int i = t; i < 512; i += TPB) sW3[i] = W3[i];
  if (t < 16) sb3[t] = b3[t];
  if (t < 32) sW4[t] = W4[t];
  if (t < 2)  sb4[t] = b4[t];
  __syncthreads();
  int n = blockIdx.x*TPB + t;
  if (n >= N) return;
  float hin[32];
  #pragma unroll
  for (int j = 0; j < 32; j++) hin[j] = h[(size_t)n*32 + j];
  float m[16];
  #pragma unroll
  for (int o = 0; o < 16; o++){
    float a = sb3[o];
    #pragma unroll
    for (int j = 0; j < 32; j++) a += hin[j]*sW3[j*16 + o];
    m[o] = fmaxf(a, 0.f);
  }
  float o0 = sb4[0], o1 = sb4[1];
  #pragma unroll
  for (int j = 0; j < 16; j++){ o0 += m[j]*sW4[j*2]; o1 += m[j]*sW4[j*2+1]; }
  out[(size_t)n*2]     = o0;
  out[(size_t)n*2 + 1] = o1;
}

extern "C" void kernel_launch(void* const* d_in, const int* in_sizes, int n_in,
                              void* d_out, int out_size, void* d_ws, size_t ws_size,
                              hipStream_t stream){
  const float* x     = (const float*)d_in[0];
  const int*   ei    = (const int*)  d_in[1];
  const float* fc1_w = (const float*)d_in[2];
  const float* fc1_b = (const float*)d_in[3];
  const float* fc2_w = (const float*)d_in[4];
  const float* fc2_b = (const float*)d_in[5];
  const float* a_iw[4] = {(const float*)d_in[6],  (const float*)d_in[9],  (const float*)d_in[12], (const float*)d_in[15]};
  const float* a_rw[4] = {(const float*)d_in[7],  (const float*)d_in[10], (const float*)d_in[13], (const float*)d_in[16]};
  const float* a_b [4] = {(const float*)d_in[8],  (const float*)d_in[11], (const float*)d_in[14], (const float*)d_in[17]};
  const float* fc3_w = (const float*)d_in[18];
  const float* fc3_b = (const float*)d_in[19];
  const float* fc4_w = (const float*)d_in[20];
  const float* fc4_b = (const float*)d_in[21];

  const int N = in_sizes[0] / 4;
  const int E = in_sizes[1] / 2;
  const int* row = ei;
  const int* col = ei + E;
  const int NB = (N + 255) >> BKT_SH;
  const int chunk = (E + NBLK_A - 1) / NBLK_A;

  char* p = (char*)d_ws;
  auto alloc = [&](size_t bytes)->void*{
    void* q = (void*)p;
    p += (bytes + 255) & ~size_t(255);
    return q;
  };
  float*    dis    = (float*)   alloc((size_t)N*4);
  int*      cnt    = (int*)     alloc((size_t)N*4);
  int*      off    = (int*)     alloc((size_t)N*4);
  const int nb     = (N + 1023) / 1024;
  int*      bsums  = (int*)     alloc((size_t)nb*4);
  int*      esrc   = (int*)     alloc((size_t)E*4);
  int2*     binned = (int2*)    alloc((size_t)E*8);
  int*      hist   = (int*)     alloc((size_t)NB*NBLK_A*4);
  int*      btot   = (int*)     alloc((size_t)NB*4);
  int*      bbase  = (int*)     alloc((size_t)(NB+1)*4);
  float*    h1     = (float*)   alloc((size_t)N*128*4);
  ushort_t* h1b    = (ushort_t*)alloc((size_t)N*128*2);
  float*    aggH1  = (float*)   alloc((size_t)N*128*4);
  float*    hmid   = (float*)   alloc((size_t)N*32*4);
  float*    h2     = (float*)   alloc((size_t)N*32*4);
  ushort_t* h2b    = (ushort_t*)alloc((size_t)N*32*2);
  float*    h3     = (float*)   alloc((size_t)N*32*4);
  ushort_t* h3b    = (ushort_t*)alloc((size_t)N*32*2);
  float*    aggS   = (float*)   alloc((size_t)N*32*4);
  float*    WpFC2  = (float*)   alloc((size_t)32*128*4);
  float*    Wp1    = (float*)   alloc((size_t)256*128*4);
  float*    Wp2    = (float*)   alloc((size_t)64*128*4);
  float*    Wp3    = (float*)   alloc((size_t)64*128*4);
  float*    Wp4    = (float*)   alloc((size_t)64*128*4);
  float*    WpA[4] = {Wp1, Wp2, Wp3, Wp4};

  // ---- atomic-free bucketed CSR build ----
  k_hist   <<<NBLK_A, TPB, 0, stream>>>(col, E, NB, chunk, hist);
  k_bs1    <<<NB, TPB, 0, stream>>>(hist, btot);
  k_bs2    <<<1, 1, 0, stream>>>(btot, NB, bbase);
  k_bin    <<<NBLK_A, TPB, 0, stream>>>(row, col, E, NB, chunk, hist, bbase, binned);
  k_cnt    <<<NB, TPB, 0, stream>>>(binned, bbase, N, cnt);
  k_scan1  <<<nb, TPB, 0, stream>>>(cnt, N, off, bsums, dis);
  k_scan2  <<<1, 1, 0, stream>>>(bsums, nb);
  k_scan3  <<<(N+TPB-1)/TPB, TPB, 0, stream>>>(off, bsums, N);
  k_scatter<<<NB, TPB, 0, stream>>>(binned, bbase, off, N, esrc);

  // weight prep (tiny)
  k_wprep_fc  <<<(32*128+TPB-1)/TPB,  TPB, 0, stream>>>(fc2_w, 32, WpFC2);
  k_wprep_arma<<<(2*128*128+TPB-1)/TPB, TPB, 0, stream>>>(a_iw[0], a_rw[0], 128, Wp1);
  for (int L = 1; L < 4; L++)
    k_wprep_arma<<<(2*32*128+TPB-1)/TPB, TPB, 0, stream>>>(a_iw[L], a_rw[L], 32, WpA[L]);

  const int gg = (N + 127) / 128;
  k_fc1<<<((size_t)N*32+TPB-1)/TPB, TPB, 0, stream>>>(x, fc1_w, fc1_b, hmid, N);
  k_gemm<32,1,1,2><<<gg, TPB, 0, stream>>>(hmid, hmid, WpFC2, fc2_b, h1, h1b, N);

  // ARMA 1 (fin=128): bf16 gather, unified GEMM -> h2 (+h2b)
  k_gatherb<128><<<(N+15)/16, TPB, 0, stream>>>((const unsigned*)h1b, off, cnt, esrc, dis, aggH1, N);
  k_gemm<128,8,4,0><<<gg, TPB, 0, stream>>>(aggH1, h1, Wp1, a_b[0], h2, h2b, N);

  // ARMA 2..4 (fin=32): ping-pong (h2,h2b) <-> (h3,h3b)
  const float* hin = h2; const ushort_t* hinb = h2b;
  float* hout = h3; ushort_t* houtb = h3b;
  for (int L = 1; L < 4; L++){
    k_gatherb<32><<<(N+63)/64, TPB, 0, stream>>>((const unsigned*)hinb, off, cnt, esrc, dis, aggS, N);
    k_gemm<32,2,1,0><<<gg, TPB, 0, stream>>>(aggS, hin, WpA[L], a_b[L], hout, houtb, N);
    const float* tf = hin; hin = hout; hout = (float*)tf;
    const ushort_t* tb = hinb; hinb = houtb; houtb = (ushort_t*)tb;
  }

  // after 3 swaps: final ARMA output in h3
  k_head<<<(N+TPB-1)/TPB, TPB, 0, stream>>>(h3, fc3_w, fc3_b, fc4_w, fc4_b, (float*)d_out, N);
}